// Round 4
// baseline (14900.980 us; speedup 1.0000x reference)
//
#include <hip/hip_runtime.h>
#include <hip/hip_bf16.h>
#include <stdint.h>

#define BB 32
#define PP 196
#define ENC 512
#define DEC 512
#define ATTD 512
#define EE 256
#define SS 128
#define VV 10000
#define TT 127    // S-1 steps
#define NBLK 256

typedef unsigned short ushort_t;
typedef unsigned int uint_t;
typedef float f32x4 __attribute__((ext_vector_type(4)));
typedef short s16x8 __attribute__((ext_vector_type(8)));

__device__ __forceinline__ float bf2f(ushort_t u) {
    uint_t x = ((uint_t)u) << 16;
    return __uint_as_float(x);
}
__device__ __forceinline__ ushort_t f2bf(float f) {
    uint_t u = __float_as_uint(f);
    uint_t r = (u + 0x7FFFu + ((u >> 16) & 1u)) >> 16;
    return (ushort_t)r;
}
__device__ __forceinline__ float ftanh(float x) {
    x = fminf(15.f, fmaxf(-15.f, x));
    float e = __expf(2.f * x);
    return (e - 1.f) / (e + 1.f);
}
__device__ __forceinline__ float fsig(float x) {
    return 1.f / (1.f + __expf(-x));
}

// ---------------- prep kernels ----------------

__global__ void k_cvt(const float* __restrict__ s, ushort_t* __restrict__ d, int n) {
    for (int i = blockIdx.x * blockDim.x + threadIdx.x; i < n; i += gridDim.x * blockDim.x)
        d[i] = f2bf(s[i]);
}

// embeds_bf[(t*32+b)*256 + e] = bf16(emb[cap[b*S+t]][e])
__global__ void k_embed_bf(const int* __restrict__ cap, const float* __restrict__ emb,
                           ushort_t* __restrict__ out) {
    const int n = TT * BB * EE;
    for (int i = blockIdx.x * blockDim.x + threadIdx.x; i < n; i += gridDim.x * blockDim.x) {
        int e = i & (EE - 1);
        int b = (i >> 8) & (BB - 1);
        int t = i >> 13;
        int tok = cap[b * SS + t];
        out[i] = f2bf(emb[(size_t)tok * EE + e]);
    }
}

// WihT_emb[k][row] = bf16(W_ih[row][k]), k < 256
__global__ void k_cvtT(const float* __restrict__ Wih, ushort_t* __restrict__ out) {
    const int n = EE * 4 * DEC;
    for (int i = blockIdx.x * blockDim.x + threadIdx.x; i < n; i += gridDim.x * blockDim.x) {
        int k = i & (EE - 1);
        int row = i >> 8;
        out[(size_t)k * (4 * DEC) + row] = f2bf(Wih[(size_t)row * (EE + ENC) + k]);
    }
}

__global__ void k_bsum(const float* __restrict__ a, const float* __restrict__ b,
                       float* __restrict__ o, int n) {
    int i = blockIdx.x * blockDim.x + threadIdx.x;
    if (i < n) o[i] = a[i] + b[i];
}

// per-b: mean over P, then h0/c0; block 0 thread 0 zeroes barrier state
__global__ __launch_bounds__(256) void k_init(const float* __restrict__ feat,
                                              const float* __restrict__ Wh, const float* __restrict__ bh,
                                              const float* __restrict__ Wc, const float* __restrict__ bc,
                                              float* __restrict__ h0, float* __restrict__ c0,
                                              int* __restrict__ bar) {
    __shared__ float ms[ENC];
    int b = blockIdx.x, t = threadIdx.x;
    if (b == 0 && t == 0) { bar[0] = 0; bar[1] = 0; }
    for (int c = t; c < ENC; c += 256) {
        float s = 0.f;
        for (int p = 0; p < PP; ++p) s += feat[((size_t)b * PP + p) * ENC + c];
        ms[c] = s * (1.f / (float)PP);
    }
    __syncthreads();
    int d0 = 2 * t;
    float ah0 = 0.f, ah1 = 0.f, ac0 = 0.f, ac1 = 0.f;
    for (int k = 0; k < ENC; ++k) {
        float mk = ms[k];
        float2 wh = *(const float2*)(Wh + (size_t)k * DEC + d0);
        float2 wc = *(const float2*)(Wc + (size_t)k * DEC + d0);
        ah0 += mk * wh.x; ah1 += mk * wh.y;
        ac0 += mk * wc.x; ac1 += mk * wc.y;
    }
    h0[b * DEC + d0] = ah0 + bh[d0];
    h0[b * DEC + d0 + 1] = ah1 + bh[d0 + 1];
    c0[b * DEC + d0] = ac0 + bc[d0];
    c0[b * DEC + d0 + 1] = ac1 + bc[d0 + 1];
}

// ---------------- bf16 MFMA GEMM (128x128 tile, BK=32, 4 waves) ----------------
// MODE 0: outb[gr*N+gc] = bf16(acc + bias[gc])
// MODE 1: outf[(b*127+t)*V + gc] = acc + bias[gc], row gr = t*32+b
template <int MODE>
__global__ __launch_bounds__(256) void k_gemm(const ushort_t* __restrict__ A,
                                              const ushort_t* __restrict__ Bm,
                                              const float* __restrict__ bias,
                                              ushort_t* __restrict__ outb,
                                              float* __restrict__ outf,
                                              int M, int N, int K) {
    __shared__ __align__(16) ushort_t As[128 * 32];
    __shared__ __align__(16) ushort_t Bs[128 * 32];

    const int tid = threadIdx.x;
    const int wid = tid >> 6, lane = tid & 63;
    const int wm = wid >> 1, wn = wid & 1;
    const int lr = lane & 15, lk = (lane >> 4) * 8;
    const int row0 = blockIdx.x * 128, col0 = blockIdx.y * 128;

    f32x4 acc[4][4];
#pragma unroll
    for (int i = 0; i < 4; ++i)
#pragma unroll
        for (int j = 0; j < 4; ++j) acc[i][j] = (f32x4){0.f, 0.f, 0.f, 0.f};

    for (int k0 = 0; k0 < K; k0 += 32) {
        {
            int r = tid >> 1, kk = (tid & 1) * 16;
            int gr = row0 + r;
            uint4 v0 = {0, 0, 0, 0}, v1 = {0, 0, 0, 0};
            if (gr < M) {
                const ushort_t* sp = A + (size_t)gr * K + k0 + kk;
                v0 = *(const uint4*)sp;
                v1 = *(const uint4*)(sp + 8);
            }
            *(uint4*)(As + r * 32 + kk) = v0;
            *(uint4*)(As + r * 32 + kk + 8) = v1;
        }
        {
            int kk = tid >> 3;
            int n = (tid & 7) * 16;
            const ushort_t* sp = Bm + (size_t)(k0 + kk) * N + col0 + n;
            ushort_t tmp[16];
            if (col0 + n + 16 <= N) {
                *(uint4*)tmp = *(const uint4*)sp;
                *(uint4*)(tmp + 8) = *(const uint4*)(sp + 8);
            } else {
#pragma unroll
                for (int j = 0; j < 16; ++j) {
                    int c = col0 + n + j;
                    tmp[j] = (c < N) ? sp[j] : (ushort_t)0;
                }
            }
#pragma unroll
            for (int j = 0; j < 16; ++j) Bs[(n + j) * 32 + kk] = tmp[j];
        }
        __syncthreads();
        s16x8 af[4], bfr[4];
#pragma unroll
        for (int i = 0; i < 4; ++i)
            af[i] = *(const s16x8*)(As + (wm * 64 + i * 16 + lr) * 32 + lk);
#pragma unroll
        for (int j = 0; j < 4; ++j)
            bfr[j] = *(const s16x8*)(Bs + (wn * 64 + j * 16 + lr) * 32 + lk);
#pragma unroll
        for (int i = 0; i < 4; ++i)
#pragma unroll
            for (int j = 0; j < 4; ++j)
                acc[i][j] = __builtin_amdgcn_mfma_f32_16x16x32_bf16(af[i], bfr[j], acc[i][j], 0, 0, 0);
        __syncthreads();
    }

    const int lrow = (lane >> 4) * 4;
#pragma unroll
    for (int i = 0; i < 4; ++i) {
#pragma unroll
        for (int j = 0; j < 4; ++j) {
            int gr0 = row0 + wm * 64 + i * 16 + lrow;
            int gc = col0 + wn * 64 + j * 16 + lr;
#pragma unroll
            for (int r = 0; r < 4; ++r) {
                int gr = gr0 + r;
                if (gr < M && gc < N) {
                    float v = acc[i][j][r] + bias[gc];
                    if (MODE == 0) {
                        outb[(size_t)gr * N + gc] = f2bf(v);
                    } else {
                        int t = gr >> 5, b = gr & 31;
                        outf[((size_t)(b * TT + t)) * VV + gc] = v;
                    }
                }
            }
        }
    }
}

// ---------------- persistent recurrent kernel ----------------

__device__ __forceinline__ void gbar(int* cnt, int* gen) {
    __syncthreads();
    if (threadIdx.x == 0) {
        __threadfence();   // release: drain this block's writes to device scope
        int g = __hip_atomic_load(gen, __ATOMIC_RELAXED, __HIP_MEMORY_SCOPE_AGENT);
        int a = __hip_atomic_fetch_add(cnt, 1, __ATOMIC_RELAXED, __HIP_MEMORY_SCOPE_AGENT);
        if (a == NBLK - 1) {
            __hip_atomic_store(cnt, 0, __ATOMIC_RELAXED, __HIP_MEMORY_SCOPE_AGENT);
            __hip_atomic_fetch_add(gen, 1, __ATOMIC_RELEASE, __HIP_MEMORY_SCOPE_AGENT);
        } else {
            while (__hip_atomic_load(gen, __ATOMIC_RELAXED, __HIP_MEMORY_SCOPE_AGENT) == g)
                __builtin_amdgcn_s_sleep(1);
        }
        __threadfence();   // acquire: invalidate stale cached lines
    }
    __syncthreads();
}

// 256 blocks x 256 threads, persistent over all 127 steps.
// Phase A: a = h@Wdec + bdec (block = (b, jc)); zero ctxU/Ssum
// Phase B: scores -> exp -> atomic ctxU/Ssum  (block = (b, pc))
// Phase C: gates GEMV (K=1024: ctx|h) + LSTM pointwise (block = dz, d-pair)
__global__ __launch_bounds__(256, 1) void k_steps(
    const ushort_t* __restrict__ fp, const ushort_t* __restrict__ fb,
    const ushort_t* __restrict__ Wdec, const float* __restrict__ bdec,
    const float* __restrict__ vatt, const float* __restrict__ bfull,
    const float* __restrict__ Wih, const float* __restrict__ Whh,
    const ushort_t* __restrict__ gemb,
    float* __restrict__ hbuf, float* __restrict__ cbuf,
    float* __restrict__ a_glob, float* __restrict__ ctxU, float* __restrict__ Ssum,
    ushort_t* __restrict__ Hb, int* __restrict__ bar) {

    __shared__ __align__(16) float xs[BB * 1032];   // 132,096 B (stride-padded x = [ctx|h])
    __shared__ __align__(16) float aux[2048];       // 8 KB scratch; aux[1536..2047] = persistent vatt

    const int bid = blockIdx.x, tid = threadIdx.x;
    int* bcnt = bar;
    int* bgen = bar + 1;

    const float bfull_r = bfull[0];

    // phase A/B ids
    const int bA = bid >> 3;
    const int jc = bid & 7;
    const int pc = bid & 7;
    const int cnt_b = (pc < 4) ? 25 : 24;
    const int p0 = (pc < 4) ? pc * 25 : 100 + (pc - 4) * 24;
    // phase A reduction consts
    const int jq = tid & 15, kh = tid >> 4;
    const float bdec_r = (tid < 64) ? bdec[jc * 64 + tid] : 0.f;
    // phase B consts
    const int pl = tid >> 3, ks = tid & 7;
    // phase C consts: tid = b*8 + ds*4 + kq
    const int cb = tid >> 3, cds = (tid >> 2) & 1, ckq = tid & 3;
    const int dz = bid;
    const int dd = dz * 2 + cds;
    const int ck0 = ckq * 256;
    const float* wB[4];
#pragma unroll
    for (int g = 0; g < 4; ++g) {
        int row = g * DEC + dd;
        wB[g] = (ckq < 2) ? (Wih + (size_t)row * (EE + ENC) + EE + ck0)
                          : (Whh + (size_t)row * DEC + (ck0 - 512));
    }

    // persistent vatt in LDS
    aux[1536 + tid] = vatt[tid];
    aux[1536 + 256 + tid] = vatt[tid + 256];
    __syncthreads();

    for (int st = 0; st < TT; ++st) {
        const float* h_in = hbuf + (size_t)(st & 1) * BB * DEC;
        float* h_out = hbuf + (size_t)((st + 1) & 1) * BB * DEC;

        // ---------- phase A ----------
        {
            float* hs = aux;            // [512]
            float* red = aux + 512;     // [64][16]
            hs[tid] = h_in[bA * DEC + tid];
            hs[tid + 256] = h_in[bA * DEC + tid + 256];
            __syncthreads();
            const int j0 = jc * 64 + jq * 4;
            f32x4 a4 = (f32x4){0.f, 0.f, 0.f, 0.f};
            const ushort_t* wp = Wdec + (size_t)(kh * 32) * ATTD + j0;
#pragma unroll 8
            for (int k = 0; k < 32; ++k) {
                uint2 w = *(const uint2*)(wp + (size_t)k * ATTD);
                float hk = hs[kh * 32 + k];
                a4[0] += hk * bf2f((ushort_t)(w.x & 0xffffu));
                a4[1] += hk * bf2f((ushort_t)(w.x >> 16));
                a4[2] += hk * bf2f((ushort_t)(w.y & 0xffffu));
                a4[3] += hk * bf2f((ushort_t)(w.y >> 16));
            }
#pragma unroll
            for (int c = 0; c < 4; ++c) red[(jq * 4 + c) * 16 + kh] = a4[c];
            __syncthreads();
            if (tid < 64) {
                float s = 0.f;
#pragma unroll
                for (int k2 = 0; k2 < 16; ++k2) s += red[tid * 16 + k2];
                a_glob[bA * ATTD + jc * 64 + tid] = s + bdec_r;
                ctxU[bA * ENC + jc * 64 + tid] = 0.f;
                if (jc == 0 && tid == 0) Ssum[bA] = 0.f;
            }
        }
        gbar(bcnt, bgen);

        // ---------- phase B ----------
        {
            float* as_ = aux;            // [512]
            float* vs = aux + 1536;      // persistent
            float* ep = aux + 1024;      // [32]
            as_[tid] = a_glob[bA * ATTD + tid];
            as_[tid + 256] = a_glob[bA * ATTD + tid + 256];
            __syncthreads();
            float acc = 0.f;
            if (pl < cnt_b) {
                const int p = p0 + pl;
                const ushort_t* fr = fp + ((size_t)bA * PP + p) * ATTD + ks * 64;
#pragma unroll 8
                for (int kk = 0; kk < 64; kk += 2) {
                    int kk2 = (kk + 8 * ks) & 63;
                    uint_t fv = *(const uint_t*)(fr + kk2);
                    int k = ks * 64 + kk2;
                    acc += ftanh(bf2f((ushort_t)(fv & 0xffffu)) + as_[k]) * vs[k];
                    acc += ftanh(bf2f((ushort_t)(fv >> 16)) + as_[k + 1]) * vs[k + 1];
                }
            }
            acc += __shfl_xor(acc, 1);
            acc += __shfl_xor(acc, 2);
            acc += __shfl_xor(acc, 4);
            if (ks == 0) ep[pl] = (pl < cnt_b) ? __expf(acc + bfull_r) : 0.f;
            __syncthreads();
            if (tid < 32) {
                float v = ep[tid];
#pragma unroll
                for (int off = 16; off > 0; off >>= 1) v += __shfl_xor(v, off);
                if (tid == 0) atomicAdd(Ssum + bA, v);
            }
            float c0 = 0.f, c1 = 0.f;
            const ushort_t* fbp = fb + ((size_t)bA * PP + p0) * ENC;
            for (int p2 = 0; p2 < cnt_b; ++p2) {
                float e2 = ep[p2];
                c0 += e2 * bf2f(fbp[(size_t)p2 * ENC + tid]);
                c1 += e2 * bf2f(fbp[(size_t)p2 * ENC + tid + 256]);
            }
            atomicAdd(ctxU + bA * ENC + tid, c0);
            atomicAdd(ctxU + bA * ENC + tid + 256, c1);
        }
        gbar(bcnt, bgen);

        // ---------- phase C ----------
        {
            if (tid < 32) aux[tid] = 1.f / Ssum[tid];
            __syncthreads();
            // stage x = [ctx_norm(512) | h(512)] -> xs[b][1024], stride 1032
#pragma unroll 4
            for (int m = 0; m < 32; ++m) {
                int i2 = (m * 256 + tid) * 4;
                int b2 = i2 >> 10, k = i2 & 1023;
                f32x4 v4;
                if (k < 512) {
                    v4 = *(const f32x4*)(ctxU + b2 * ENC + k);
                    float is = aux[b2];
                    v4 *= is;
                } else {
                    v4 = *(const f32x4*)(h_in + b2 * DEC + (k - 512));
                }
                *(f32x4*)(xs + b2 * 1032 + k) = v4;
            }
            __syncthreads();

            const float* xp = xs + cb * 1032 + ck0;
            f32x4 a0 = (f32x4){0.f,0.f,0.f,0.f}, a1 = a0, a2 = a0, a3 = a0;
#pragma unroll 8
            for (int i = 0; i < 64; ++i) {
                int ii = ((i + 9 * ckq) & 63) * 4;
                f32x4 x4 = *(const f32x4*)(xp + ii);
                a0 += x4 * *(const f32x4*)(wB[0] + ii);
                a1 += x4 * *(const f32x4*)(wB[1] + ii);
                a2 += x4 * *(const f32x4*)(wB[2] + ii);
                a3 += x4 * *(const f32x4*)(wB[3] + ii);
            }
            float s0 = a0[0] + a0[1] + a0[2] + a0[3];
            float s1 = a1[0] + a1[1] + a1[2] + a1[3];
            float s2 = a2[0] + a2[1] + a2[2] + a2[3];
            float s3 = a3[0] + a3[1] + a3[2] + a3[3];
            s0 += __shfl_xor(s0, 1); s0 += __shfl_xor(s0, 2);
            s1 += __shfl_xor(s1, 1); s1 += __shfl_xor(s1, 2);
            s2 += __shfl_xor(s2, 1); s2 += __shfl_xor(s2, 2);
            s3 += __shfl_xor(s3, 1); s3 += __shfl_xor(s3, 2);
            if (ckq == 0) {
                const size_t trow = (size_t)st * BB + cb;
                float gi = s0 + bf2f(gemb[trow * (4 * DEC) + 0 * DEC + dd]);
                float gf = s1 + bf2f(gemb[trow * (4 * DEC) + 1 * DEC + dd]);
                float gg = s2 + bf2f(gemb[trow * (4 * DEC) + 2 * DEC + dd]);
                float go = s3 + bf2f(gemb[trow * (4 * DEC) + 3 * DEC + dd]);
                float cold = cbuf[cb * DEC + dd];
                float cn = fsig(gf) * cold + fsig(gi) * ftanh(gg);
                float hn = fsig(go) * ftanh(cn);
                cbuf[cb * DEC + dd] = cn;
                h_out[cb * DEC + dd] = hn;
                Hb[trow * DEC + dd] = f2bf(hn);
            }
        }
        gbar(bcnt, bgen);
    }
}

// ---------------- launch ----------------

extern "C" void kernel_launch(void* const* d_in, const int* in_sizes, int n_in,
                              void* d_out, int out_size, void* d_ws, size_t ws_size,
                              hipStream_t stream) {
    const float* features  = (const float*)d_in[0];
    const int*   captions  = (const int*)d_in[1];
    const float* emb       = (const float*)d_in[2];
    const float* W_enc_att = (const float*)d_in[3];
    const float* b_enc_att = (const float*)d_in[4];
    const float* W_dec_att = (const float*)d_in[5];
    const float* b_dec_att = (const float*)d_in[6];
    const float* v_att     = (const float*)d_in[7];
    const float* b_full    = (const float*)d_in[8];
    const float* W_init_h  = (const float*)d_in[9];
    const float* b_init_h  = (const float*)d_in[10];
    const float* W_init_c  = (const float*)d_in[11];
    const float* b_init_c  = (const float*)d_in[12];
    const float* W_ih      = (const float*)d_in[13];
    const float* W_hh      = (const float*)d_in[14];
    const float* b_ih      = (const float*)d_in[15];
    const float* b_hh      = (const float*)d_in[16];
    const float* W_fcn     = (const float*)d_in[17];
    const float* b_fcn     = (const float*)d_in[18];
    float* out = (float*)d_out;
    char* ws = (char*)d_ws;

    size_t o = 0;
    ushort_t* Wfcn_b  = (ushort_t*)(ws + o); o += (size_t)DEC * VV * 2;          // 10,240,000
    ushort_t* Wenc_b  = (ushort_t*)(ws + o); o += (size_t)ENC * ATTD * 2;        // 524,288
    ushort_t* Wdec_b  = (ushort_t*)(ws + o); o += (size_t)DEC * ATTD * 2;        // 524,288
    ushort_t* fb      = (ushort_t*)(ws + o); o += (size_t)BB * PP * ENC * 2;     // 6,422,528
    ushort_t* fp_b    = (ushort_t*)(ws + o); o += (size_t)BB * PP * ATTD * 2;    // 6,422,528
    ushort_t* emb_bf  = (ushort_t*)(ws + o); o += (size_t)TT * BB * EE * 2;      // 2,080,768
    ushort_t* WihT    = (ushort_t*)(ws + o); o += (size_t)EE * 4 * DEC * 2;      // 1,048,576
    ushort_t* gembuf  = (ushort_t*)(ws + o); o += (size_t)TT * BB * 4 * DEC * 2; // 16,646,144
    float*    bsum    = (float*)(ws + o);    o += (size_t)4 * DEC * 4;           // 8,192
    ushort_t* Hb      = (ushort_t*)(ws + o); o += (size_t)TT * BB * DEC * 2;     // 4,161,536
    float*    hbuf    = (float*)(ws + o);    o += (size_t)2 * BB * DEC * 4;      // 131,072
    float*    cbuf    = (float*)(ws + o);    o += (size_t)BB * DEC * 4;          // 65,536
    float*    a_glob  = (float*)(ws + o);    o += (size_t)BB * ATTD * 4;         // 65,536
    float*    ctxU    = (float*)(ws + o);    o += (size_t)BB * ENC * 4;          // 65,536
    float*    Ssum    = (float*)(ws + o);    o += (size_t)BB * 4 + 64;           // pad
    int*      bar     = (int*)(ws + o);      o += 128;

    // prep
    k_cvt<<<2048, 256, 0, stream>>>(W_fcn, Wfcn_b, DEC * VV);
    k_cvt<<<256, 256, 0, stream>>>(W_enc_att, Wenc_b, ENC * ATTD);
    k_cvt<<<256, 256, 0, stream>>>(W_dec_att, Wdec_b, DEC * ATTD);
    k_cvt<<<2048, 256, 0, stream>>>(features, fb, BB * PP * ENC);
    k_embed_bf<<<1024, 256, 0, stream>>>(captions, emb, emb_bf);
    k_cvtT<<<1024, 256, 0, stream>>>(W_ih, WihT);
    k_bsum<<<8, 256, 0, stream>>>(b_ih, b_hh, bsum, 4 * DEC);
    k_init<<<32, 256, 0, stream>>>(features, W_init_h, b_init_h, W_init_c, b_init_c,
                                   hbuf, cbuf, bar);
    // feat_proj = features @ W_enc_att + b_enc_att (bf16)
    k_gemm<0><<<dim3((BB * PP) / 128, ATTD / 128), 256, 0, stream>>>(
        fb, Wenc_b, b_enc_att, fp_b, nullptr, BB * PP, ATTD, ENC);
    // gates_emb = embeds @ W_ih[:, :256]^T + (b_ih + b_hh)  (bf16)
    k_gemm<0><<<dim3((TT * BB + 127) / 128, (4 * DEC) / 128), 256, 0, stream>>>(
        emb_bf, WihT, bsum, gembuf, nullptr, TT * BB, 4 * DEC, EE);

    // persistent recurrent kernel: all 127 steps
    k_steps<<<NBLK, 256, 0, stream>>>(fp_b, fb, Wdec_b, b_dec_att, v_att, b_full,
                                      W_ih, W_hh, gembuf, hbuf, cbuf,
                                      a_glob, ctxU, Ssum, Hb, bar);

    // out = H @ W_fcn + b_fcn, scattered to [b][t][v]
    k_gemm<1><<<dim3((TT * BB + 127) / 128, (VV + 127) / 128), 256, 0, stream>>>(
        Hb, Wfcn_b, b_fcn, nullptr, out, TT * BB, VV, DEC);
}

// Round 5
// 8869.710 us; speedup vs baseline: 1.6800x; 1.6800x over previous
//
#include <hip/hip_runtime.h>
#include <hip/hip_bf16.h>
#include <stdint.h>

#define BB 32
#define PP 196
#define ENC 512
#define DEC 512
#define ATTD 512
#define EE 256
#define SS 128
#define VV 10000
#define TT 127    // S-1 steps
#define NBLK 256

typedef unsigned short ushort_t;
typedef unsigned int uint_t;
typedef float f32x4 __attribute__((ext_vector_type(4)));
typedef short s16x8 __attribute__((ext_vector_type(8)));

__device__ __forceinline__ float bf2f(ushort_t u) {
    uint_t x = ((uint_t)u) << 16;
    return __uint_as_float(x);
}
__device__ __forceinline__ ushort_t f2bf(float f) {
    uint_t u = __float_as_uint(f);
    uint_t r = (u + 0x7FFFu + ((u >> 16) & 1u)) >> 16;
    return (ushort_t)r;
}
__device__ __forceinline__ float ftanh(float x) {
    x = fminf(15.f, fmaxf(-15.f, x));
    float e = __expf(2.f * x);
    return (e - 1.f) / (e + 1.f);
}
__device__ __forceinline__ float fsig(float x) {
    return 1.f / (1.f + __expf(-x));
}

// ---------------- prep kernels ----------------

__global__ void k_cvt(const float* __restrict__ s, ushort_t* __restrict__ d, int n) {
    for (int i = blockIdx.x * blockDim.x + threadIdx.x; i < n; i += gridDim.x * blockDim.x)
        d[i] = f2bf(s[i]);
}

__global__ void k_embed_bf(const int* __restrict__ cap, const float* __restrict__ emb,
                           ushort_t* __restrict__ out) {
    const int n = TT * BB * EE;
    for (int i = blockIdx.x * blockDim.x + threadIdx.x; i < n; i += gridDim.x * blockDim.x) {
        int e = i & (EE - 1);
        int b = (i >> 8) & (BB - 1);
        int t = i >> 13;
        int tok = cap[b * SS + t];
        out[i] = f2bf(emb[(size_t)tok * EE + e]);
    }
}

__global__ void k_cvtT(const float* __restrict__ Wih, ushort_t* __restrict__ out) {
    const int n = EE * 4 * DEC;
    for (int i = blockIdx.x * blockDim.x + threadIdx.x; i < n; i += gridDim.x * blockDim.x) {
        int k = i & (EE - 1);
        int row = i >> 8;
        out[(size_t)k * (4 * DEC) + row] = f2bf(Wih[(size_t)row * (EE + ENC) + k]);
    }
}

__global__ void k_bsum(const float* __restrict__ a, const float* __restrict__ b,
                       float* __restrict__ o, int n) {
    int i = blockIdx.x * blockDim.x + threadIdx.x;
    if (i < n) o[i] = a[i] + b[i];
}

// per-b: mean over P, then h0/c0; block 0 zeroes all barrier state
__global__ __launch_bounds__(256) void k_init(const float* __restrict__ feat,
                                              const float* __restrict__ Wh, const float* __restrict__ bh,
                                              const float* __restrict__ Wc, const float* __restrict__ bc,
                                              float* __restrict__ h0, float* __restrict__ c0,
                                              int* __restrict__ bar) {
    __shared__ float ms[ENC];
    int b = blockIdx.x, t = threadIdx.x;
    if (b == 0) {
        for (int i = t; i < 4096; i += 256) bar[i] = 0;
    }
    for (int c = t; c < ENC; c += 256) {
        float s = 0.f;
        for (int p = 0; p < PP; ++p) s += feat[((size_t)b * PP + p) * ENC + c];
        ms[c] = s * (1.f / (float)PP);
    }
    __syncthreads();
    int d0 = 2 * t;
    float ah0 = 0.f, ah1 = 0.f, ac0 = 0.f, ac1 = 0.f;
    for (int k = 0; k < ENC; ++k) {
        float mk = ms[k];
        float2 wh = *(const float2*)(Wh + (size_t)k * DEC + d0);
        float2 wc = *(const float2*)(Wc + (size_t)k * DEC + d0);
        ah0 += mk * wh.x; ah1 += mk * wh.y;
        ac0 += mk * wc.x; ac1 += mk * wc.y;
    }
    h0[b * DEC + d0] = ah0 + bh[d0];
    h0[b * DEC + d0 + 1] = ah1 + bh[d0 + 1];
    c0[b * DEC + d0] = ac0 + bc[d0];
    c0[b * DEC + d0 + 1] = ac1 + bc[d0 + 1];
}

// ---------------- bf16 MFMA GEMM (128x128 tile, BK=32, 4 waves) ----------------
template <int MODE>
__global__ __launch_bounds__(256) void k_gemm(const ushort_t* __restrict__ A,
                                              const ushort_t* __restrict__ Bm,
                                              const float* __restrict__ bias,
                                              ushort_t* __restrict__ outb,
                                              float* __restrict__ outf,
                                              int M, int N, int K) {
    __shared__ __align__(16) ushort_t As[128 * 32];
    __shared__ __align__(16) ushort_t Bs[128 * 32];

    const int tid = threadIdx.x;
    const int wid = tid >> 6, lane = tid & 63;
    const int wm = wid >> 1, wn = wid & 1;
    const int lr = lane & 15, lk = (lane >> 4) * 8;
    const int row0 = blockIdx.x * 128, col0 = blockIdx.y * 128;

    f32x4 acc[4][4];
#pragma unroll
    for (int i = 0; i < 4; ++i)
#pragma unroll
        for (int j = 0; j < 4; ++j) acc[i][j] = (f32x4){0.f, 0.f, 0.f, 0.f};

    for (int k0 = 0; k0 < K; k0 += 32) {
        {
            int r = tid >> 1, kk = (tid & 1) * 16;
            int gr = row0 + r;
            uint4 v0 = {0, 0, 0, 0}, v1 = {0, 0, 0, 0};
            if (gr < M) {
                const ushort_t* sp = A + (size_t)gr * K + k0 + kk;
                v0 = *(const uint4*)sp;
                v1 = *(const uint4*)(sp + 8);
            }
            *(uint4*)(As + r * 32 + kk) = v0;
            *(uint4*)(As + r * 32 + kk + 8) = v1;
        }
        {
            int kk = tid >> 3;
            int n = (tid & 7) * 16;
            const ushort_t* sp = Bm + (size_t)(k0 + kk) * N + col0 + n;
            ushort_t tmp[16];
            if (col0 + n + 16 <= N) {
                *(uint4*)tmp = *(const uint4*)sp;
                *(uint4*)(tmp + 8) = *(const uint4*)(sp + 8);
            } else {
#pragma unroll
                for (int j = 0; j < 16; ++j) {
                    int c = col0 + n + j;
                    tmp[j] = (c < N) ? sp[j] : (ushort_t)0;
                }
            }
#pragma unroll
            for (int j = 0; j < 16; ++j) Bs[(n + j) * 32 + kk] = tmp[j];
        }
        __syncthreads();
        s16x8 af[4], bfr[4];
#pragma unroll
        for (int i = 0; i < 4; ++i)
            af[i] = *(const s16x8*)(As + (wm * 64 + i * 16 + lr) * 32 + lk);
#pragma unroll
        for (int j = 0; j < 4; ++j)
            bfr[j] = *(const s16x8*)(Bs + (wn * 64 + j * 16 + lr) * 32 + lk);
#pragma unroll
        for (int i = 0; i < 4; ++i)
#pragma unroll
            for (int j = 0; j < 4; ++j)
                acc[i][j] = __builtin_amdgcn_mfma_f32_16x16x32_bf16(af[i], bfr[j], acc[i][j], 0, 0, 0);
        __syncthreads();
    }

    const int lrow = (lane >> 4) * 4;
#pragma unroll
    for (int i = 0; i < 4; ++i) {
#pragma unroll
        for (int j = 0; j < 4; ++j) {
            int gr0 = row0 + wm * 64 + i * 16 + lrow;
            int gc = col0 + wn * 64 + j * 16 + lr;
#pragma unroll
            for (int r = 0; r < 4; ++r) {
                int gr = gr0 + r;
                if (gr < M && gc < N) {
                    float v = acc[i][j][r] + bias[gc];
                    if (MODE == 0) {
                        outb[(size_t)gr * N + gc] = f2bf(v);
                    } else {
                        int t = gr >> 5, b = gr & 31;
                        outf[((size_t)(b * TT + t)) * VV + gc] = v;
                    }
                }
            }
        }
    }
}

// ---------------- persistent recurrent kernel ----------------
// bar layout (ints, 128B-separated slots):
//   bar[0]            : gen (global barrier broadcast)
//   bar[32]           : super counter (level 2)
//   bar[64 + g*32]    : level-1 counters, g = bid>>4, 16 groups of 16
//   bar[576 + bA*32]  : per-b group counters, bA = bid>>3, 32 groups of 8

__device__ __forceinline__ void gbar_global(int* bar, int e) {
    __syncthreads();
    if (threadIdx.x == 0) {
        __threadfence();   // release: writeback this XCD's dirty L2 lines
        int g = (int)(blockIdx.x >> 4);
        int a = __hip_atomic_fetch_add(bar + 64 + g * 32, 1, __ATOMIC_RELAXED,
                                       __HIP_MEMORY_SCOPE_AGENT);
        if (a == e * 16 - 1) {
            int s = __hip_atomic_fetch_add(bar + 32, 1, __ATOMIC_RELAXED,
                                           __HIP_MEMORY_SCOPE_AGENT);
            if (s == e * 16 - 1)
                __hip_atomic_store(bar, e, __ATOMIC_RELEASE, __HIP_MEMORY_SCOPE_AGENT);
        }
        while (__hip_atomic_load(bar, __ATOMIC_RELAXED, __HIP_MEMORY_SCOPE_AGENT) < e)
            __builtin_amdgcn_s_sleep(8);
        __threadfence();   // acquire: invalidate stale L2 lines
    }
    __syncthreads();
}

__device__ __forceinline__ void gbar_group(int* bar, int grp, int e) {
    __syncthreads();
    if (threadIdx.x == 0) {
        __threadfence();
        int* cnt = bar + 576 + grp * 32;
        __hip_atomic_fetch_add(cnt, 1, __ATOMIC_RELAXED, __HIP_MEMORY_SCOPE_AGENT);
        while (__hip_atomic_load(cnt, __ATOMIC_RELAXED, __HIP_MEMORY_SCOPE_AGENT) < e * 8)
            __builtin_amdgcn_s_sleep(2);
        __threadfence();
    }
    __syncthreads();
}

// aux layout (floats):
#define AUX_HS 0        // [512] h (phase A) / a (phase B)
#define AUX_RED 512     // [64][17] phase A reduction (stride 17: kills 16-way conflict)
#define AUX_EP 1600     // [32] exp values
#define AUX_INV 1632    // [32] 1/Ssum
#define AUX_VS 1664     // [512] persistent v_att
#define AUX_TOT 2176

__global__ __launch_bounds__(256, 1) void k_steps(
    const ushort_t* __restrict__ fp, const ushort_t* __restrict__ fb,
    const ushort_t* __restrict__ Wdec, const float* __restrict__ bdec,
    const float* __restrict__ vatt, const float* __restrict__ bfull,
    const float* __restrict__ Wih, const float* __restrict__ Whh,
    const ushort_t* __restrict__ gemb,
    float* __restrict__ hbuf, float* __restrict__ cbuf,
    float* __restrict__ a_glob, float* __restrict__ ctxU, float* __restrict__ Ssum,
    ushort_t* __restrict__ Hb, int* __restrict__ bar) {

    __shared__ __align__(16) float xs[BB * 1032];   // 132,096 B: x = [ctx|h] per b, stride 1032
    __shared__ __align__(16) float aux[AUX_TOT];    // 8,704 B

    const int bid = blockIdx.x, tid = threadIdx.x;
    const float bfull_r = bfull[0];

    // phase A/B ids: group = 8 blocks sharing bA
    const int bA = bid >> 3;
    const int jc = bid & 7;
    const int pc = bid & 7;
    const int cnt_b = (pc < 4) ? 25 : 24;
    const int p0 = (pc < 4) ? pc * 25 : 100 + (pc - 4) * 24;
    const int jq = tid & 15, kh = tid >> 4;
    const float bdec_r = (tid < 64) ? bdec[jc * 64 + tid] : 0.f;
    const int pl = tid >> 3, ks = tid & 7;
    // phase C ids: tid = cb*8 + cds*4 + ckq
    const int cb = tid >> 3, cds = (tid >> 2) & 1, ckq = tid & 3;
    const int dz = bid;
    const int dd = dz * 2 + cds;
    const int ck0 = ckq * 256;
    const float* wB[4];
#pragma unroll
    for (int g = 0; g < 4; ++g) {
        int row = g * DEC + dd;
        wB[g] = (ckq < 2) ? (Wih + (size_t)row * (EE + ENC) + EE + ck0)
                          : (Whh + (size_t)row * DEC + (ck0 - 512));
    }

    // persistent v_att in LDS
    aux[AUX_VS + tid] = vatt[tid];
    aux[AUX_VS + 256 + tid] = vatt[tid + 256];
    __syncthreads();

    for (int st = 0; st < TT; ++st) {
        const float* h_in = hbuf + (size_t)(st & 1) * BB * DEC;
        float* h_out = hbuf + (size_t)((st + 1) & 1) * BB * DEC;

        // ---------- phase A: a = h@Wdec + bdec (this block: 64 j's of bA) ----------
        {
            float* hs = aux + AUX_HS;
            float* red = aux + AUX_RED;
            hs[tid] = h_in[bA * DEC + tid];
            hs[tid + 256] = h_in[bA * DEC + tid + 256];
            __syncthreads();
            const int j0 = jc * 64 + jq * 4;
            f32x4 a4 = (f32x4){0.f, 0.f, 0.f, 0.f};
            const ushort_t* wp = Wdec + (size_t)(kh * 32) * ATTD + j0;
#pragma unroll 8
            for (int k = 0; k < 32; ++k) {
                uint2 w = *(const uint2*)(wp + (size_t)k * ATTD);
                float hk = hs[kh * 32 + k];
                a4[0] += hk * bf2f((ushort_t)(w.x & 0xffffu));
                a4[1] += hk * bf2f((ushort_t)(w.x >> 16));
                a4[2] += hk * bf2f((ushort_t)(w.y & 0xffffu));
                a4[3] += hk * bf2f((ushort_t)(w.y >> 16));
            }
#pragma unroll
            for (int c = 0; c < 4; ++c) red[(jq * 4 + c) * 17 + kh] = a4[c];
            __syncthreads();
            if (tid < 64) {
                float s = 0.f;
#pragma unroll
                for (int k2 = 0; k2 < 16; ++k2) s += red[tid * 17 + k2];
                a_glob[bA * ATTD + jc * 64 + tid] = s + bdec_r;
                ctxU[bA * ENC + jc * 64 + tid] = 0.f;
                if (jc == 0 && tid == 0) Ssum[bA] = 0.f;
            }
            // overlap: stage h-half of xs (h stable for whole step)
#pragma unroll 4
            for (int m = 0; m < 16; ++m) {
                int idx = m * 256 + tid;
                int b2 = idx >> 7;
                int k = (idx & 127) * 4;
                *(f32x4*)(xs + b2 * 1032 + 512 + k) = *(const f32x4*)(h_in + b2 * DEC + k);
            }
        }
        gbar_group(bar, bA, st + 1);

        // ---------- phase B: scores -> exp -> atomic ctxU/Ssum (24-25 p's) ----------
        {
            float* as_ = aux + AUX_HS;
            float* vs = aux + AUX_VS;
            float* ep = aux + AUX_EP;
            as_[tid] = a_glob[bA * ATTD + tid];
            as_[tid + 256] = a_glob[bA * ATTD + tid + 256];
            __syncthreads();
            float acc = 0.f;
            if (pl < cnt_b) {
                const int p = p0 + pl;
                const ushort_t* fr = fp + ((size_t)bA * PP + p) * ATTD + ks * 64;
#pragma unroll 8
                for (int kk = 0; kk < 64; kk += 2) {
                    int kk2 = (kk + 8 * ks) & 63;
                    uint_t fv = *(const uint_t*)(fr + kk2);
                    int k = ks * 64 + kk2;
                    float2 av = *(const float2*)(as_ + k);
                    float2 vv = *(const float2*)(vs + k);
                    acc += ftanh(bf2f((ushort_t)(fv & 0xffffu)) + av.x) * vv.x;
                    acc += ftanh(bf2f((ushort_t)(fv >> 16)) + av.y) * vv.y;
                }
            }
            acc += __shfl_xor(acc, 1);
            acc += __shfl_xor(acc, 2);
            acc += __shfl_xor(acc, 4);
            if (ks == 0) ep[pl] = (pl < cnt_b) ? __expf(acc + bfull_r) : 0.f;
            __syncthreads();
            if (tid < 32) {
                float v = ep[tid];
#pragma unroll
                for (int off = 16; off > 0; off >>= 1) v += __shfl_xor(v, off);
                if (tid == 0) atomicAdd(Ssum + bA, v);
            }
            float c0 = 0.f, c1 = 0.f;
            const ushort_t* fbp = fb + ((size_t)bA * PP + p0) * ENC;
            for (int p2 = 0; p2 < cnt_b; ++p2) {
                float e2 = ep[p2];
                c0 += e2 * bf2f(fbp[(size_t)p2 * ENC + tid]);
                c1 += e2 * bf2f(fbp[(size_t)p2 * ENC + tid + 256]);
            }
            atomicAdd(ctxU + bA * ENC + tid, c0);
            atomicAdd(ctxU + bA * ENC + tid + 256, c1);
        }
        gbar_global(bar, 2 * st + 1);

        // ---------- phase C: gates GEMV (K=1024) + LSTM pointwise ----------
        {
            float* invS = aux + AUX_INV;
            if (tid < 32) invS[tid] = 1.f / Ssum[tid];
            __syncthreads();
            // stage ctx-half of xs (h-half already staged in phase A)
#pragma unroll 4
            for (int m = 0; m < 16; ++m) {
                int idx = m * 256 + tid;
                int b2 = idx >> 7;
                int k = (idx & 127) * 4;
                f32x4 v4 = *(const f32x4*)(ctxU + b2 * ENC + k);
                v4 *= invS[b2];
                *(f32x4*)(xs + b2 * 1032 + k) = v4;
            }
            __syncthreads();

            const float* xp = xs + cb * 1032 + ck0;
            f32x4 a0 = (f32x4){0.f,0.f,0.f,0.f}, a1 = a0, a2 = a0, a3 = a0;
#pragma unroll 8
            for (int i = 0; i < 64; ++i) {
                int ii = ((i + 9 * ckq) & 63) * 4;
                f32x4 x4 = *(const f32x4*)(xp + ii);
                a0 += x4 * *(const f32x4*)(wB[0] + ii);
                a1 += x4 * *(const f32x4*)(wB[1] + ii);
                a2 += x4 * *(const f32x4*)(wB[2] + ii);
                a3 += x4 * *(const f32x4*)(wB[3] + ii);
            }
            float s0 = a0[0] + a0[1] + a0[2] + a0[3];
            float s1 = a1[0] + a1[1] + a1[2] + a1[3];
            float s2 = a2[0] + a2[1] + a2[2] + a2[3];
            float s3 = a3[0] + a3[1] + a3[2] + a3[3];
            s0 += __shfl_xor(s0, 1); s0 += __shfl_xor(s0, 2);
            s1 += __shfl_xor(s1, 1); s1 += __shfl_xor(s1, 2);
            s2 += __shfl_xor(s2, 1); s2 += __shfl_xor(s2, 2);
            s3 += __shfl_xor(s3, 1); s3 += __shfl_xor(s3, 2);
            if (ckq == 0) {
                const size_t trow = (size_t)st * BB + cb;
                float gi = s0 + bf2f(gemb[trow * (4 * DEC) + 0 * DEC + dd]);
                float gf = s1 + bf2f(gemb[trow * (4 * DEC) + 1 * DEC + dd]);
                float gg = s2 + bf2f(gemb[trow * (4 * DEC) + 2 * DEC + dd]);
                float go = s3 + bf2f(gemb[trow * (4 * DEC) + 3 * DEC + dd]);
                float cold = cbuf[cb * DEC + dd];
                float cn = fsig(gf) * cold + fsig(gi) * ftanh(gg);
                float hn = fsig(go) * ftanh(cn);
                cbuf[cb * DEC + dd] = cn;
                h_out[cb * DEC + dd] = hn;
                Hb[trow * DEC + dd] = f2bf(hn);
            }
        }
        gbar_global(bar, 2 * st + 2);
    }
}

// ---------------- launch ----------------

extern "C" void kernel_launch(void* const* d_in, const int* in_sizes, int n_in,
                              void* d_out, int out_size, void* d_ws, size_t ws_size,
                              hipStream_t stream) {
    const float* features  = (const float*)d_in[0];
    const int*   captions  = (const int*)d_in[1];
    const float* emb       = (const float*)d_in[2];
    const float* W_enc_att = (const float*)d_in[3];
    const float* b_enc_att = (const float*)d_in[4];
    const float* W_dec_att = (const float*)d_in[5];
    const float* b_dec_att = (const float*)d_in[6];
    const float* v_att     = (const float*)d_in[7];
    const float* b_full    = (const float*)d_in[8];
    const float* W_init_h  = (const float*)d_in[9];
    const float* b_init_h  = (const float*)d_in[10];
    const float* W_init_c  = (const float*)d_in[11];
    const float* b_init_c  = (const float*)d_in[12];
    const float* W_ih      = (const float*)d_in[13];
    const float* W_hh      = (const float*)d_in[14];
    const float* b_ih      = (const float*)d_in[15];
    const float* b_hh      = (const float*)d_in[16];
    const float* W_fcn     = (const float*)d_in[17];
    const float* b_fcn     = (const float*)d_in[18];
    float* out = (float*)d_out;
    char* ws = (char*)d_ws;

    size_t o = 0;
    ushort_t* Wfcn_b  = (ushort_t*)(ws + o); o += (size_t)DEC * VV * 2;
    ushort_t* Wenc_b  = (ushort_t*)(ws + o); o += (size_t)ENC * ATTD * 2;
    ushort_t* Wdec_b  = (ushort_t*)(ws + o); o += (size_t)DEC * ATTD * 2;
    ushort_t* fb      = (ushort_t*)(ws + o); o += (size_t)BB * PP * ENC * 2;
    ushort_t* fp_b    = (ushort_t*)(ws + o); o += (size_t)BB * PP * ATTD * 2;
    ushort_t* emb_bf  = (ushort_t*)(ws + o); o += (size_t)TT * BB * EE * 2;
    ushort_t* WihT    = (ushort_t*)(ws + o); o += (size_t)EE * 4 * DEC * 2;
    ushort_t* gembuf  = (ushort_t*)(ws + o); o += (size_t)TT * BB * 4 * DEC * 2;
    float*    bsum    = (float*)(ws + o);    o += (size_t)4 * DEC * 4;
    ushort_t* Hb      = (ushort_t*)(ws + o); o += (size_t)TT * BB * DEC * 2;
    float*    hbuf    = (float*)(ws + o);    o += (size_t)2 * BB * DEC * 4;
    float*    cbuf    = (float*)(ws + o);    o += (size_t)BB * DEC * 4;
    float*    a_glob  = (float*)(ws + o);    o += (size_t)BB * ATTD * 4;
    float*    ctxU    = (float*)(ws + o);    o += (size_t)BB * ENC * 4;
    float*    Ssum    = (float*)(ws + o);    o += (size_t)BB * 4 + 64;
    int*      bar     = (int*)(ws + o);      o += 4096 * 4;   // 16 KB barrier state

    // prep
    k_cvt<<<2048, 256, 0, stream>>>(W_fcn, Wfcn_b, DEC * VV);
    k_cvt<<<256, 256, 0, stream>>>(W_enc_att, Wenc_b, ENC * ATTD);
    k_cvt<<<256, 256, 0, stream>>>(W_dec_att, Wdec_b, DEC * ATTD);
    k_cvt<<<2048, 256, 0, stream>>>(features, fb, BB * PP * ENC);
    k_embed_bf<<<1024, 256, 0, stream>>>(captions, emb, emb_bf);
    k_cvtT<<<1024, 256, 0, stream>>>(W_ih, WihT);
    k_bsum<<<8, 256, 0, stream>>>(b_ih, b_hh, bsum, 4 * DEC);
    k_init<<<32, 256, 0, stream>>>(features, W_init_h, b_init_h, W_init_c, b_init_c,
                                   hbuf, cbuf, bar);
    // feat_proj = features @ W_enc_att + b_enc_att (bf16)
    k_gemm<0><<<dim3((BB * PP) / 128, ATTD / 128), 256, 0, stream>>>(
        fb, Wenc_b, b_enc_att, fp_b, nullptr, BB * PP, ATTD, ENC);
    // gates_emb = embeds @ W_ih[:, :256]^T + (b_ih + b_hh)  (bf16)
    k_gemm<0><<<dim3((TT * BB + 127) / 128, (4 * DEC) / 128), 256, 0, stream>>>(
        emb_bf, WihT, bsum, gembuf, nullptr, TT * BB, 4 * DEC, EE);

    // persistent recurrent kernel: all 127 steps
    k_steps<<<NBLK, 256, 0, stream>>>(fp_b, fb, Wdec_b, b_dec_att, v_att, b_full,
                                      W_ih, W_hh, gembuf, hbuf, cbuf,
                                      a_glob, ctxU, Ssum, Hb, bar);

    // out = H @ W_fcn + b_fcn, scattered to [b][t][v]
    k_gemm<1><<<dim3((TT * BB + 127) / 128, (VV + 127) / 128), 256, 0, stream>>>(
        Hb, Wfcn_b, b_fcn, nullptr, out, TT * BB, VV, DEC);
}

// Round 6
// 7589.986 us; speedup vs baseline: 1.9632x; 1.1686x over previous
//
#include <hip/hip_runtime.h>
#include <hip/hip_bf16.h>
#include <stdint.h>

#define BB 32
#define PP 196
#define ENC 512
#define DEC 512
#define ATTD 512
#define EE 256
#define SS 128
#define VV 10000
#define TT 127    // S-1 steps
#define NBLK 256

typedef unsigned short ushort_t;
typedef unsigned int uint_t;
typedef unsigned long long u64_t;
typedef float f32x4 __attribute__((ext_vector_type(4)));
typedef short s16x8 __attribute__((ext_vector_type(8)));

__device__ __forceinline__ float bf2f(ushort_t u) {
    uint_t x = ((uint_t)u) << 16;
    return __uint_as_float(x);
}
__device__ __forceinline__ ushort_t f2bf(float f) {
    uint_t u = __float_as_uint(f);
    uint_t r = (u + 0x7FFFu + ((u >> 16) & 1u)) >> 16;
    return (ushort_t)r;
}
__device__ __forceinline__ float ftanh(float x) {
    x = fminf(15.f, fmaxf(-15.f, x));
    float e = __expf(2.f * x);
    return (e - 1.f) / (e + 1.f);
}
__device__ __forceinline__ float fsig(float x) {
    return 1.f / (1.f + __expf(-x));
}

// ---- coherence helpers: agent-scope relaxed atomics (bypass L1/L2, no fences) ----
__device__ __forceinline__ float aload1(const float* p) {
    return __hip_atomic_load(p, __ATOMIC_RELAXED, __HIP_MEMORY_SCOPE_AGENT);
}
__device__ __forceinline__ void astore1(float* p, float v) {
    __hip_atomic_store(p, v, __ATOMIC_RELAXED, __HIP_MEMORY_SCOPE_AGENT);
}
__device__ __forceinline__ float2 aload2(const float* p) {
    u64_t v = __hip_atomic_load((const u64_t*)p, __ATOMIC_RELAXED, __HIP_MEMORY_SCOPE_AGENT);
    float2 r;
    r.x = __uint_as_float((uint_t)v);
    r.y = __uint_as_float((uint_t)(v >> 32));
    return r;
}
__device__ __forceinline__ void afadd(float* p, float v) {
    __hip_atomic_fetch_add(p, v, __ATOMIC_RELAXED, __HIP_MEMORY_SCOPE_AGENT);
}
__device__ __forceinline__ void wait_vm() {
    asm volatile("s_waitcnt vmcnt(0)" ::: "memory");
}

// ---------------- prep kernels ----------------

__global__ void k_cvt(const float* __restrict__ s, ushort_t* __restrict__ d, int n) {
    for (int i = blockIdx.x * blockDim.x + threadIdx.x; i < n; i += gridDim.x * blockDim.x)
        d[i] = f2bf(s[i]);
}

__global__ void k_embed_bf(const int* __restrict__ cap, const float* __restrict__ emb,
                           ushort_t* __restrict__ out) {
    const int n = TT * BB * EE;
    for (int i = blockIdx.x * blockDim.x + threadIdx.x; i < n; i += gridDim.x * blockDim.x) {
        int e = i & (EE - 1);
        int b = (i >> 8) & (BB - 1);
        int t = i >> 13;
        int tok = cap[b * SS + t];
        out[i] = f2bf(emb[(size_t)tok * EE + e]);
    }
}

__global__ void k_cvtT(const float* __restrict__ Wih, ushort_t* __restrict__ out) {
    const int n = EE * 4 * DEC;
    for (int i = blockIdx.x * blockDim.x + threadIdx.x; i < n; i += gridDim.x * blockDim.x) {
        int k = i & (EE - 1);
        int row = i >> 8;
        out[(size_t)k * (4 * DEC) + row] = f2bf(Wih[(size_t)row * (EE + ENC) + k]);
    }
}

__global__ void k_bsum(const float* __restrict__ a, const float* __restrict__ b,
                       float* __restrict__ o, int n) {
    int i = blockIdx.x * blockDim.x + threadIdx.x;
    if (i < n) o[i] = a[i] + b[i];
}

// per-b: mean over P, then h0/c0; block 0 zeroes all barrier state
__global__ __launch_bounds__(256) void k_init(const float* __restrict__ feat,
                                              const float* __restrict__ Wh, const float* __restrict__ bh,
                                              const float* __restrict__ Wc, const float* __restrict__ bc,
                                              float* __restrict__ h0, float* __restrict__ c0,
                                              int* __restrict__ bar) {
    __shared__ float ms[ENC];
    int b = blockIdx.x, t = threadIdx.x;
    if (b == 0) {
        for (int i = t; i < 4096; i += 256) bar[i] = 0;
    }
    for (int c = t; c < ENC; c += 256) {
        float s = 0.f;
        for (int p = 0; p < PP; ++p) s += feat[((size_t)b * PP + p) * ENC + c];
        ms[c] = s * (1.f / (float)PP);
    }
    __syncthreads();
    int d0 = 2 * t;
    float ah0 = 0.f, ah1 = 0.f, ac0 = 0.f, ac1 = 0.f;
    for (int k = 0; k < ENC; ++k) {
        float mk = ms[k];
        float2 wh = *(const float2*)(Wh + (size_t)k * DEC + d0);
        float2 wc = *(const float2*)(Wc + (size_t)k * DEC + d0);
        ah0 += mk * wh.x; ah1 += mk * wh.y;
        ac0 += mk * wc.x; ac1 += mk * wc.y;
    }
    h0[b * DEC + d0] = ah0 + bh[d0];
    h0[b * DEC + d0 + 1] = ah1 + bh[d0 + 1];
    c0[b * DEC + d0] = ac0 + bc[d0];
    c0[b * DEC + d0 + 1] = ac1 + bc[d0 + 1];
}

// ---------------- bf16 MFMA GEMM (128x128 tile, BK=32, 4 waves) ----------------
template <int MODE>
__global__ __launch_bounds__(256) void k_gemm(const ushort_t* __restrict__ A,
                                              const ushort_t* __restrict__ Bm,
                                              const float* __restrict__ bias,
                                              ushort_t* __restrict__ outb,
                                              float* __restrict__ outf,
                                              int M, int N, int K) {
    __shared__ __align__(16) ushort_t As[128 * 32];
    __shared__ __align__(16) ushort_t Bs[128 * 32];

    const int tid = threadIdx.x;
    const int wid = tid >> 6, lane = tid & 63;
    const int wm = wid >> 1, wn = wid & 1;
    const int lr = lane & 15, lk = (lane >> 4) * 8;
    const int row0 = blockIdx.x * 128, col0 = blockIdx.y * 128;

    f32x4 acc[4][4];
#pragma unroll
    for (int i = 0; i < 4; ++i)
#pragma unroll
        for (int j = 0; j < 4; ++j) acc[i][j] = (f32x4){0.f, 0.f, 0.f, 0.f};

    for (int k0 = 0; k0 < K; k0 += 32) {
        {
            int r = tid >> 1, kk = (tid & 1) * 16;
            int gr = row0 + r;
            uint4 v0 = {0, 0, 0, 0}, v1 = {0, 0, 0, 0};
            if (gr < M) {
                const ushort_t* sp = A + (size_t)gr * K + k0 + kk;
                v0 = *(const uint4*)sp;
                v1 = *(const uint4*)(sp + 8);
            }
            *(uint4*)(As + r * 32 + kk) = v0;
            *(uint4*)(As + r * 32 + kk + 8) = v1;
        }
        {
            int kk = tid >> 3;
            int n = (tid & 7) * 16;
            const ushort_t* sp = Bm + (size_t)(k0 + kk) * N + col0 + n;
            ushort_t tmp[16];
            if (col0 + n + 16 <= N) {
                *(uint4*)tmp = *(const uint4*)sp;
                *(uint4*)(tmp + 8) = *(const uint4*)(sp + 8);
            } else {
#pragma unroll
                for (int j = 0; j < 16; ++j) {
                    int c = col0 + n + j;
                    tmp[j] = (c < N) ? sp[j] : (ushort_t)0;
                }
            }
#pragma unroll
            for (int j = 0; j < 16; ++j) Bs[(n + j) * 32 + kk] = tmp[j];
        }
        __syncthreads();
        s16x8 af[4], bfr[4];
#pragma unroll
        for (int i = 0; i < 4; ++i)
            af[i] = *(const s16x8*)(As + (wm * 64 + i * 16 + lr) * 32 + lk);
#pragma unroll
        for (int j = 0; j < 4; ++j)
            bfr[j] = *(const s16x8*)(Bs + (wn * 64 + j * 16 + lr) * 32 + lk);
#pragma unroll
        for (int i = 0; i < 4; ++i)
#pragma unroll
            for (int j = 0; j < 4; ++j)
                acc[i][j] = __builtin_amdgcn_mfma_f32_16x16x32_bf16(af[i], bfr[j], acc[i][j], 0, 0, 0);
        __syncthreads();
    }

    const int lrow = (lane >> 4) * 4;
#pragma unroll
    for (int i = 0; i < 4; ++i) {
#pragma unroll
        for (int j = 0; j < 4; ++j) {
            int gr0 = row0 + wm * 64 + i * 16 + lrow;
            int gc = col0 + wn * 64 + j * 16 + lr;
#pragma unroll
            for (int r = 0; r < 4; ++r) {
                int gr = gr0 + r;
                if (gr < M && gc < N) {
                    float v = acc[i][j][r] + bias[gc];
                    if (MODE == 0) {
                        outb[(size_t)gr * N + gc] = f2bf(v);
                    } else {
                        int t = gr >> 5, b = gr & 31;
                        outf[((size_t)(b * TT + t)) * VV + gc] = v;
                    }
                }
            }
        }
    }
}

// ---------------- persistent recurrent kernel ----------------
// bar layout (ints, 128B-separated slots):
//   bar[0]            : gen (global barrier broadcast)
//   bar[32]           : super counter (level 2)
//   bar[64 + g*32]    : level-1 counters, g = bid>>4, 16 groups of 16
//   bar[576 + bA*32]  : per-b group counters, bA = bid&31, 32 groups of 8 (same-XCD)
//
// No __threadfence anywhere: all cross-block data moves via agent-scope relaxed
// atomics (coherent at LLC); each wave drains vmcnt(0) before s_barrier so data
// is complete at the coherence point before any counter bump is visible.

__device__ __forceinline__ void gbar_global(int* bar, int e) {
    wait_vm();
    __syncthreads();
    if (threadIdx.x == 0) {
        int g = (int)(blockIdx.x >> 4);
        int a = __hip_atomic_fetch_add(bar + 64 + g * 32, 1, __ATOMIC_RELAXED,
                                       __HIP_MEMORY_SCOPE_AGENT);
        if (a == e * 16 - 1) {
            int s = __hip_atomic_fetch_add(bar + 32, 1, __ATOMIC_RELAXED,
                                           __HIP_MEMORY_SCOPE_AGENT);
            if (s == e * 16 - 1)
                __hip_atomic_store(bar, e, __ATOMIC_RELAXED, __HIP_MEMORY_SCOPE_AGENT);
        }
        while (__hip_atomic_load(bar, __ATOMIC_RELAXED, __HIP_MEMORY_SCOPE_AGENT) < e)
            __builtin_amdgcn_s_sleep(4);
    }
    __syncthreads();
}

__device__ __forceinline__ void gbar_group(int* bar, int grp, int e) {
    wait_vm();
    __syncthreads();
    if (threadIdx.x == 0) {
        int* cnt = bar + 576 + grp * 32;
        __hip_atomic_fetch_add(cnt, 1, __ATOMIC_RELAXED, __HIP_MEMORY_SCOPE_AGENT);
        while (__hip_atomic_load(cnt, __ATOMIC_RELAXED, __HIP_MEMORY_SCOPE_AGENT) < e * 8)
            __builtin_amdgcn_s_sleep(2);
    }
    __syncthreads();
}

// aux layout (floats):
#define AUX_HS 0        // [512] h (phase A) / a (phase B)
#define AUX_RED 512     // [64][17] phase A reduction (stride 17)
#define AUX_EP 1600     // [32] exp values
#define AUX_INV 1632    // [32] 1/Ssum
#define AUX_VS 1664     // [512] persistent v_att
#define AUX_TOT 2176

__global__ __launch_bounds__(256, 1) void k_steps(
    const ushort_t* __restrict__ fp, const ushort_t* __restrict__ fb,
    const ushort_t* __restrict__ Wdec, const float* __restrict__ bdec,
    const float* __restrict__ vatt, const float* __restrict__ bfull,
    const float* __restrict__ Wih, const float* __restrict__ Whh,
    const ushort_t* __restrict__ gemb,
    float* __restrict__ hbuf, float* __restrict__ cbuf,
    float* __restrict__ a_glob, float* __restrict__ ctxU, float* __restrict__ Ssum,
    ushort_t* __restrict__ Hb, int* __restrict__ bar) {

    __shared__ __align__(16) float xs[BB * 1032];   // x = [ctx|h] per b, stride 1032
    __shared__ __align__(16) float aux[AUX_TOT];

    const int bid = blockIdx.x, tid = threadIdx.x;
    const float bfull_r = bfull[0];

    // phase A/B ids: group = 8 blocks {bA + 32j} sharing bA (same XCD: bid%8 const)
    const int bA = bid & 31;
    const int jc = bid >> 5;
    const int pc = bid >> 5;
    const int cnt_b = (pc < 4) ? 25 : 24;
    const int p0 = (pc < 4) ? pc * 25 : 100 + (pc - 4) * 24;
    const int jq = tid & 15, kh = tid >> 4;
    const float bdec_r = (tid < 64) ? bdec[jc * 64 + tid] : 0.f;
    const int pl = tid >> 3, ks = tid & 7;
    // phase C ids: tid = cb*8 + cds*4 + ckq
    const int cb = tid >> 3, cds = (tid >> 2) & 1, ckq = tid & 3;
    const int dz = bid;
    const int dd = dz * 2 + cds;
    const int ck0 = ckq * 256;
    const float* wB[4];
#pragma unroll
    for (int g = 0; g < 4; ++g) {
        int row = g * DEC + dd;
        wB[g] = (ckq < 2) ? (Wih + (size_t)row * (EE + ENC) + EE + ck0)
                          : (Whh + (size_t)row * DEC + (ck0 - 512));
    }

    // persistent v_att in LDS
    aux[AUX_VS + tid] = vatt[tid];
    aux[AUX_VS + 256 + tid] = vatt[tid + 256];
    __syncthreads();

    for (int st = 0; st < TT; ++st) {
        const float* h_in = hbuf + (size_t)(st & 1) * BB * DEC;
        float* h_out = hbuf + (size_t)((st + 1) & 1) * BB * DEC;

        // ---------- phase A: a = h@Wdec + bdec (this block: 64 j's of bA) ----------
        {
            float* hs = aux + AUX_HS;
            float* red = aux + AUX_RED;
            {
                float2 hv = aload2(h_in + bA * DEC + 2 * tid);
                hs[2 * tid] = hv.x;
                hs[2 * tid + 1] = hv.y;
            }
            __syncthreads();
            const int j0 = jc * 64 + jq * 4;
            f32x4 a4 = (f32x4){0.f, 0.f, 0.f, 0.f};
            const ushort_t* wp = Wdec + (size_t)(kh * 32) * ATTD + j0;
#pragma unroll 8
            for (int k = 0; k < 32; ++k) {
                uint2 w = *(const uint2*)(wp + (size_t)k * ATTD);
                float hk = hs[kh * 32 + k];
                a4[0] += hk * bf2f((ushort_t)(w.x & 0xffffu));
                a4[1] += hk * bf2f((ushort_t)(w.x >> 16));
                a4[2] += hk * bf2f((ushort_t)(w.y & 0xffffu));
                a4[3] += hk * bf2f((ushort_t)(w.y >> 16));
            }
#pragma unroll
            for (int c = 0; c < 4; ++c) red[(jq * 4 + c) * 17 + kh] = a4[c];
            __syncthreads();
            if (tid < 64) {
                float s = 0.f;
#pragma unroll
                for (int k2 = 0; k2 < 16; ++k2) s += red[tid * 17 + k2];
                astore1(a_glob + bA * ATTD + jc * 64 + tid, s + bdec_r);
                astore1(ctxU + bA * ENC + jc * 64 + tid, 0.f);
                if (jc == 0 && tid == 0) astore1(Ssum + bA, 0.f);
            }
            // overlap: stage h-half of xs (h stable for whole step)
#pragma unroll 4
            for (int m = 0; m < 16; ++m) {
                int idx = m * 256 + tid;
                int b2 = idx >> 7;
                int k = (idx & 127) * 4;
                float2 v0 = aload2(h_in + b2 * DEC + k);
                float2 v1 = aload2(h_in + b2 * DEC + k + 2);
                f32x4 v4 = (f32x4){v0.x, v0.y, v1.x, v1.y};
                *(f32x4*)(xs + b2 * 1032 + 512 + k) = v4;
            }
        }
        gbar_group(bar, bA, st + 1);

        // ---------- phase B: scores -> exp -> atomic ctxU/Ssum (24-25 p's) ----------
        {
            float* as_ = aux + AUX_HS;
            float* vs = aux + AUX_VS;
            float* ep = aux + AUX_EP;
            {
                float2 av = aload2(a_glob + bA * ATTD + 2 * tid);
                as_[2 * tid] = av.x;
                as_[2 * tid + 1] = av.y;
            }
            __syncthreads();
            float acc = 0.f;
            if (pl < cnt_b) {
                const int p = p0 + pl;
                const ushort_t* fr = fp + ((size_t)bA * PP + p) * ATTD + ks * 64;
#pragma unroll 8
                for (int kk = 0; kk < 64; kk += 2) {
                    int kk2 = (kk + 8 * ks) & 63;
                    uint_t fv = *(const uint_t*)(fr + kk2);
                    int k = ks * 64 + kk2;
                    float2 av = *(const float2*)(as_ + k);
                    float2 vv = *(const float2*)(vs + k);
                    acc += ftanh(bf2f((ushort_t)(fv & 0xffffu)) + av.x) * vv.x;
                    acc += ftanh(bf2f((ushort_t)(fv >> 16)) + av.y) * vv.y;
                }
            }
            acc += __shfl_xor(acc, 1);
            acc += __shfl_xor(acc, 2);
            acc += __shfl_xor(acc, 4);
            if (ks == 0) ep[pl] = (pl < cnt_b) ? __expf(acc + bfull_r) : 0.f;
            __syncthreads();
            if (tid < 32) {
                float v = ep[tid];
#pragma unroll
                for (int off = 16; off > 0; off >>= 1) v += __shfl_xor(v, off);
                if (tid == 0) afadd(Ssum + bA, v);
            }
            float c0 = 0.f, c1 = 0.f;
            const ushort_t* fbp = fb + ((size_t)bA * PP + p0) * ENC;
            for (int p2 = 0; p2 < cnt_b; ++p2) {
                float e2 = ep[p2];
                c0 += e2 * bf2f(fbp[(size_t)p2 * ENC + tid]);
                c1 += e2 * bf2f(fbp[(size_t)p2 * ENC + tid + 256]);
            }
            afadd(ctxU + bA * ENC + tid, c0);
            afadd(ctxU + bA * ENC + tid + 256, c1);
        }
        gbar_global(bar, 2 * st + 1);

        // ---------- phase C: gates GEMV (K=1024) + LSTM pointwise ----------
        {
            float* invS = aux + AUX_INV;
            if (tid < 32) invS[tid] = 1.f / aload1(Ssum + tid);
            __syncthreads();
            // stage ctx-half of xs (h-half already staged in phase A)
#pragma unroll 4
            for (int m = 0; m < 16; ++m) {
                int idx = m * 256 + tid;
                int b2 = idx >> 7;
                int k = (idx & 127) * 4;
                float2 v0 = aload2(ctxU + b2 * ENC + k);
                float2 v1 = aload2(ctxU + b2 * ENC + k + 2);
                f32x4 v4 = (f32x4){v0.x, v0.y, v1.x, v1.y};
                v4 *= invS[b2];
                *(f32x4*)(xs + b2 * 1032 + k) = v4;
            }
            __syncthreads();

            const float* xp = xs + cb * 1032 + ck0;
            f32x4 a0 = (f32x4){0.f,0.f,0.f,0.f}, a1 = a0, a2 = a0, a3 = a0;
#pragma unroll 8
            for (int i = 0; i < 64; ++i) {
                int ii = ((i + 9 * ckq) & 63) * 4;
                f32x4 x4 = *(const f32x4*)(xp + ii);
                a0 += x4 * *(const f32x4*)(wB[0] + ii);
                a1 += x4 * *(const f32x4*)(wB[1] + ii);
                a2 += x4 * *(const f32x4*)(wB[2] + ii);
                a3 += x4 * *(const f32x4*)(wB[3] + ii);
            }
            float s0 = a0[0] + a0[1] + a0[2] + a0[3];
            float s1 = a1[0] + a1[1] + a1[2] + a1[3];
            float s2 = a2[0] + a2[1] + a2[2] + a2[3];
            float s3 = a3[0] + a3[1] + a3[2] + a3[3];
            s0 += __shfl_xor(s0, 1); s0 += __shfl_xor(s0, 2);
            s1 += __shfl_xor(s1, 1); s1 += __shfl_xor(s1, 2);
            s2 += __shfl_xor(s2, 1); s2 += __shfl_xor(s2, 2);
            s3 += __shfl_xor(s3, 1); s3 += __shfl_xor(s3, 2);
            if (ckq == 0) {
                const size_t trow = (size_t)st * BB + cb;
                float gi = s0 + bf2f(gemb[trow * (4 * DEC) + 0 * DEC + dd]);
                float gf = s1 + bf2f(gemb[trow * (4 * DEC) + 1 * DEC + dd]);
                float gg = s2 + bf2f(gemb[trow * (4 * DEC) + 2 * DEC + dd]);
                float go = s3 + bf2f(gemb[trow * (4 * DEC) + 3 * DEC + dd]);
                float cold = cbuf[cb * DEC + dd];
                float cn = fsig(gf) * cold + fsig(gi) * ftanh(gg);
                float hn = fsig(go) * ftanh(cn);
                cbuf[cb * DEC + dd] = cn;
                astore1(h_out + cb * DEC + dd, hn);
                Hb[trow * DEC + dd] = f2bf(hn);
            }
        }
        gbar_global(bar, 2 * st + 2);
    }
}

// ---------------- launch ----------------

extern "C" void kernel_launch(void* const* d_in, const int* in_sizes, int n_in,
                              void* d_out, int out_size, void* d_ws, size_t ws_size,
                              hipStream_t stream) {
    const float* features  = (const float*)d_in[0];
    const int*   captions  = (const int*)d_in[1];
    const float* emb       = (const float*)d_in[2];
    const float* W_enc_att = (const float*)d_in[3];
    const float* b_enc_att = (const float*)d_in[4];
    const float* W_dec_att = (const float*)d_in[5];
    const float* b_dec_att = (const float*)d_in[6];
    const float* v_att     = (const float*)d_in[7];
    const float* b_full    = (const float*)d_in[8];
    const float* W_init_h  = (const float*)d_in[9];
    const float* b_init_h  = (const float*)d_in[10];
    const float* W_init_c  = (const float*)d_in[11];
    const float* b_init_c  = (const float*)d_in[12];
    const float* W_ih      = (const float*)d_in[13];
    const float* W_hh      = (const float*)d_in[14];
    const float* b_ih      = (const float*)d_in[15];
    const float* b_hh      = (const float*)d_in[16];
    const float* W_fcn     = (const float*)d_in[17];
    const float* b_fcn     = (const float*)d_in[18];
    float* out = (float*)d_out;
    char* ws = (char*)d_ws;

    size_t o = 0;
    ushort_t* Wfcn_b  = (ushort_t*)(ws + o); o += (size_t)DEC * VV * 2;
    ushort_t* Wenc_b  = (ushort_t*)(ws + o); o += (size_t)ENC * ATTD * 2;
    ushort_t* Wdec_b  = (ushort_t*)(ws + o); o += (size_t)DEC * ATTD * 2;
    ushort_t* fb      = (ushort_t*)(ws + o); o += (size_t)BB * PP * ENC * 2;
    ushort_t* fp_b    = (ushort_t*)(ws + o); o += (size_t)BB * PP * ATTD * 2;
    ushort_t* emb_bf  = (ushort_t*)(ws + o); o += (size_t)TT * BB * EE * 2;
    ushort_t* WihT    = (ushort_t*)(ws + o); o += (size_t)EE * 4 * DEC * 2;
    ushort_t* gembuf  = (ushort_t*)(ws + o); o += (size_t)TT * BB * 4 * DEC * 2;
    float*    bsum    = (float*)(ws + o);    o += (size_t)4 * DEC * 4;
    ushort_t* Hb      = (ushort_t*)(ws + o); o += (size_t)TT * BB * DEC * 2;
    float*    hbuf    = (float*)(ws + o);    o += (size_t)2 * BB * DEC * 4;
    float*    cbuf    = (float*)(ws + o);    o += (size_t)BB * DEC * 4;
    float*    a_glob  = (float*)(ws + o);    o += (size_t)BB * ATTD * 4;
    float*    ctxU    = (float*)(ws + o);    o += (size_t)BB * ENC * 4;
    float*    Ssum    = (float*)(ws + o);    o += (size_t)BB * 4 + 64;
    int*      bar     = (int*)(ws + o);      o += 4096 * 4;   // 16 KB barrier state

    // prep
    k_cvt<<<2048, 256, 0, stream>>>(W_fcn, Wfcn_b, DEC * VV);
    k_cvt<<<256, 256, 0, stream>>>(W_enc_att, Wenc_b, ENC * ATTD);
    k_cvt<<<256, 256, 0, stream>>>(W_dec_att, Wdec_b, DEC * ATTD);
    k_cvt<<<2048, 256, 0, stream>>>(features, fb, BB * PP * ENC);
    k_embed_bf<<<1024, 256, 0, stream>>>(captions, emb, emb_bf);
    k_cvtT<<<1024, 256, 0, stream>>>(W_ih, WihT);
    k_bsum<<<8, 256, 0, stream>>>(b_ih, b_hh, bsum, 4 * DEC);
    k_init<<<32, 256, 0, stream>>>(features, W_init_h, b_init_h, W_init_c, b_init_c,
                                   hbuf, cbuf, bar);
    // feat_proj = features @ W_enc_att + b_enc_att (bf16)
    k_gemm<0><<<dim3((BB * PP) / 128, ATTD / 128), 256, 0, stream>>>(
        fb, Wenc_b, b_enc_att, fp_b, nullptr, BB * PP, ATTD, ENC);
    // gates_emb = embeds @ W_ih[:, :256]^T + (b_ih + b_hh)  (bf16)
    k_gemm<0><<<dim3((TT * BB + 127) / 128, (4 * DEC) / 128), 256, 0, stream>>>(
        emb_bf, WihT, bsum, gembuf, nullptr, TT * BB, 4 * DEC, EE);

    // persistent recurrent kernel: all 127 steps
    k_steps<<<NBLK, 256, 0, stream>>>(fp_b, fb, Wdec_b, b_dec_att, v_att, b_full,
                                      W_ih, W_hh, gembuf, hbuf, cbuf,
                                      a_glob, ctxU, Ssum, Hb, bar);

    // out = H @ W_fcn + b_fcn, scattered to [b][t][v]
    k_gemm<1><<<dim3((TT * BB + 127) / 128, (VV + 127) / 128), 256, 0, stream>>>(
        Hb, Wfcn_b, b_fcn, nullptr, out, TT * BB, VV, DEC);
}

// Round 7
// 6118.432 us; speedup vs baseline: 2.4354x; 1.2405x over previous
//
#include <hip/hip_runtime.h>
#include <hip/hip_bf16.h>
#include <stdint.h>

#define BB 32
#define PP 196
#define ENC 512
#define DEC 512
#define ATTD 512
#define EE 256
#define SS 128
#define VV 10000
#define TT 127    // S-1 steps
#define NBLK 256

typedef unsigned short ushort_t;
typedef unsigned int uint_t;
typedef unsigned long long u64_t;
typedef float f32x4 __attribute__((ext_vector_type(4)));
typedef short s16x8 __attribute__((ext_vector_type(8)));

__device__ __forceinline__ float bf2f(ushort_t u) {
    uint_t x = ((uint_t)u) << 16;
    return __uint_as_float(x);
}
__device__ __forceinline__ ushort_t f2bf(float f) {
    uint_t u = __float_as_uint(f);
    uint_t r = (u + 0x7FFFu + ((u >> 16) & 1u)) >> 16;
    return (ushort_t)r;
}
__device__ __forceinline__ float ftanh(float x) {
    x = fminf(15.f, fmaxf(-15.f, x));
    float e = __expf(2.f * x);
    return (e - 1.f) / (e + 1.f);
}
__device__ __forceinline__ float fsig(float x) {
    return 1.f / (1.f + __expf(-x));
}

// ---- coherence helpers: agent-scope relaxed atomics (live at LLC) ----
__device__ __forceinline__ float aload1(const float* p) {
    return __hip_atomic_load(p, __ATOMIC_RELAXED, __HIP_MEMORY_SCOPE_AGENT);
}
__device__ __forceinline__ void astore1(float* p, float v) {
    __hip_atomic_store(p, v, __ATOMIC_RELAXED, __HIP_MEMORY_SCOPE_AGENT);
}
__device__ __forceinline__ float2 aload2(const float* p) {
    u64_t v = __hip_atomic_load((const u64_t*)p, __ATOMIC_RELAXED, __HIP_MEMORY_SCOPE_AGENT);
    float2 r;
    r.x = __uint_as_float((uint_t)v);
    r.y = __uint_as_float((uint_t)(v >> 32));
    return r;
}
__device__ __forceinline__ void afadd(float* p, float v) {
    __hip_atomic_fetch_add(p, v, __ATOMIC_RELAXED, __HIP_MEMORY_SCOPE_AGENT);
}

// ---------------- prep kernels ----------------

__global__ void k_cvt(const float* __restrict__ s, ushort_t* __restrict__ d, int n) {
    for (int i = blockIdx.x * blockDim.x + threadIdx.x; i < n; i += gridDim.x * blockDim.x)
        d[i] = f2bf(s[i]);
}

__global__ void k_embed_bf(const int* __restrict__ cap, const float* __restrict__ emb,
                           ushort_t* __restrict__ out) {
    const int n = TT * BB * EE;
    for (int i = blockIdx.x * blockDim.x + threadIdx.x; i < n; i += gridDim.x * blockDim.x) {
        int e = i & (EE - 1);
        int b = (i >> 8) & (BB - 1);
        int t = i >> 13;
        int tok = cap[b * SS + t];
        out[i] = f2bf(emb[(size_t)tok * EE + e]);
    }
}

__global__ void k_cvtT(const float* __restrict__ Wih, ushort_t* __restrict__ out) {
    const int n = EE * 4 * DEC;
    for (int i = blockIdx.x * blockDim.x + threadIdx.x; i < n; i += gridDim.x * blockDim.x) {
        int k = i & (EE - 1);
        int row = i >> 8;
        out[(size_t)k * (4 * DEC) + row] = f2bf(Wih[(size_t)row * (EE + ENC) + k]);
    }
}

__global__ void k_bsum(const float* __restrict__ a, const float* __restrict__ b,
                       float* __restrict__ o, int n) {
    int i = blockIdx.x * blockDim.x + threadIdx.x;
    if (i < n) o[i] = a[i] + b[i];
}

// per-b: mean over P, then h0/c0; block 0 zeroes all barrier state
__global__ __launch_bounds__(256) void k_init(const float* __restrict__ feat,
                                              const float* __restrict__ Wh, const float* __restrict__ bh,
                                              const float* __restrict__ Wc, const float* __restrict__ bc,
                                              float* __restrict__ h0, float* __restrict__ c0,
                                              int* __restrict__ bar) {
    __shared__ float ms[ENC];
    int b = blockIdx.x, t = threadIdx.x;
    if (b == 0) {
        for (int i = t; i < 4096; i += 256) bar[i] = 0;
    }
    for (int c = t; c < ENC; c += 256) {
        float s = 0.f;
        for (int p = 0; p < PP; ++p) s += feat[((size_t)b * PP + p) * ENC + c];
        ms[c] = s * (1.f / (float)PP);
    }
    __syncthreads();
    int d0 = 2 * t;
    float ah0 = 0.f, ah1 = 0.f, ac0 = 0.f, ac1 = 0.f;
    for (int k = 0; k < ENC; ++k) {
        float mk = ms[k];
        float2 wh = *(const float2*)(Wh + (size_t)k * DEC + d0);
        float2 wc = *(const float2*)(Wc + (size_t)k * DEC + d0);
        ah0 += mk * wh.x; ah1 += mk * wh.y;
        ac0 += mk * wc.x; ac1 += mk * wc.y;
    }
    h0[b * DEC + d0] = ah0 + bh[d0];
    h0[b * DEC + d0 + 1] = ah1 + bh[d0 + 1];
    c0[b * DEC + d0] = ac0 + bc[d0];
    c0[b * DEC + d0 + 1] = ac1 + bc[d0 + 1];
}

// ---------------- bf16 MFMA GEMM (128x128 tile, BK=32, 4 waves) ----------------
template <int MODE>
__global__ __launch_bounds__(256) void k_gemm(const ushort_t* __restrict__ A,
                                              const ushort_t* __restrict__ Bm,
                                              const float* __restrict__ bias,
                                              ushort_t* __restrict__ outb,
                                              float* __restrict__ outf,
                                              int M, int N, int K) {
    __shared__ __align__(16) ushort_t As[128 * 32];
    __shared__ __align__(16) ushort_t Bs[128 * 32];

    const int tid = threadIdx.x;
    const int wid = tid >> 6, lane = tid & 63;
    const int wm = wid >> 1, wn = wid & 1;
    const int lr = lane & 15, lk = (lane >> 4) * 8;
    const int row0 = blockIdx.x * 128, col0 = blockIdx.y * 128;

    f32x4 acc[4][4];
#pragma unroll
    for (int i = 0; i < 4; ++i)
#pragma unroll
        for (int j = 0; j < 4; ++j) acc[i][j] = (f32x4){0.f, 0.f, 0.f, 0.f};

    for (int k0 = 0; k0 < K; k0 += 32) {
        {
            int r = tid >> 1, kk = (tid & 1) * 16;
            int gr = row0 + r;
            uint4 v0 = {0, 0, 0, 0}, v1 = {0, 0, 0, 0};
            if (gr < M) {
                const ushort_t* sp = A + (size_t)gr * K + k0 + kk;
                v0 = *(const uint4*)sp;
                v1 = *(const uint4*)(sp + 8);
            }
            *(uint4*)(As + r * 32 + kk) = v0;
            *(uint4*)(As + r * 32 + kk + 8) = v1;
        }
        {
            int kk = tid >> 3;
            int n = (tid & 7) * 16;
            const ushort_t* sp = Bm + (size_t)(k0 + kk) * N + col0 + n;
            ushort_t tmp[16];
            if (col0 + n + 16 <= N) {
                *(uint4*)tmp = *(const uint4*)sp;
                *(uint4*)(tmp + 8) = *(const uint4*)(sp + 8);
            } else {
#pragma unroll
                for (int j = 0; j < 16; ++j) {
                    int c = col0 + n + j;
                    tmp[j] = (c < N) ? sp[j] : (ushort_t)0;
                }
            }
#pragma unroll
            for (int j = 0; j < 16; ++j) Bs[(n + j) * 32 + kk] = tmp[j];
        }
        __syncthreads();
        s16x8 af[4], bfr[4];
#pragma unroll
        for (int i = 0; i < 4; ++i)
            af[i] = *(const s16x8*)(As + (wm * 64 + i * 16 + lr) * 32 + lk);
#pragma unroll
        for (int j = 0; j < 4; ++j)
            bfr[j] = *(const s16x8*)(Bs + (wn * 64 + j * 16 + lr) * 32 + lk);
#pragma unroll
        for (int i = 0; i < 4; ++i)
#pragma unroll
            for (int j = 0; j < 4; ++j)
                acc[i][j] = __builtin_amdgcn_mfma_f32_16x16x32_bf16(af[i], bfr[j], acc[i][j], 0, 0, 0);
        __syncthreads();
    }

    const int lrow = (lane >> 4) * 4;
#pragma unroll
    for (int i = 0; i < 4; ++i) {
#pragma unroll
        for (int j = 0; j < 4; ++j) {
            int gr0 = row0 + wm * 64 + i * 16 + lrow;
            int gc = col0 + wn * 64 + j * 16 + lr;
#pragma unroll
            for (int r = 0; r < 4; ++r) {
                int gr = gr0 + r;
                if (gr < M && gc < N) {
                    float v = acc[i][j][r] + bias[gc];
                    if (MODE == 0) {
                        outb[(size_t)gr * N + gc] = f2bf(v);
                    } else {
                        int t = gr >> 5, b = gr & 31;
                        outf[((size_t)(b * TT + t)) * VV + gc] = v;
                    }
                }
            }
        }
    }
}

// ---------------- persistent recurrent kernel ----------------
// 256 blocks; group = 8 blocks serving one batch element bA.
// Decode (assumes XCD = bid%8 round-robin; correctness does NOT depend on it):
//   xcd = bid&7, pc = (bid>>3)&7, hi = bid>>6;  bA = xcd*4 + hi
// All 8 blocks of a group share bid%8 -> same XCD -> L2-local data, but all
// cross-block traffic still goes through LLC atomics (agent scope) so the
// mapping is a pure perf heuristic.
// Barriers: per-group monotonic counter at bar[576 + bA*32]; 8-way only.
// NO global barrier anywhere.

__device__ __forceinline__ void gbar8(int* cnt, int target) {
    asm volatile("s_waitcnt vmcnt(0)" ::: "memory");   // drain stores/atomics to LLC
    __syncthreads();
    if (threadIdx.x == 0) {
        __hip_atomic_fetch_add(cnt, 1, __ATOMIC_RELAXED, __HIP_MEMORY_SCOPE_AGENT);
        while (__hip_atomic_load(cnt, __ATOMIC_RELAXED, __HIP_MEMORY_SCOPE_AGENT) < target)
            __builtin_amdgcn_s_sleep(1);
    }
    __syncthreads();
}

// aux layout (floats):
#define AUX_HS 0        // [512] h (phase A) / a (phase B)
#define AUX_RED 512     // [64][17] phase A reduction (aliased with XC)
#define AUX_XC 512      // [1024] phase C x = [ctx_norm | h]
#define AUX_EP 1600     // [32] exp values
#define AUX_SS 1632     // [1] Ssum scalar
#define AUX_VS 1664     // [512] persistent v_att
#define AUX_TOT 2176

__global__ __launch_bounds__(256) void k_steps(
    const ushort_t* __restrict__ fp, const ushort_t* __restrict__ fb,
    const ushort_t* __restrict__ Wdec, const float* __restrict__ bdec,
    const float* __restrict__ vatt, const float* __restrict__ bfull,
    const float* __restrict__ Wih, const float* __restrict__ Whh,
    const ushort_t* __restrict__ gemb,
    float* __restrict__ hbuf, const float* __restrict__ cbuf,
    float* __restrict__ a_glob, float* __restrict__ ctxU, float* __restrict__ Ssum,
    ushort_t* __restrict__ Hb, int* __restrict__ bar) {

    __shared__ __align__(16) float aux[AUX_TOT];   // ~8.7 KB total LDS

    const int bid = blockIdx.x, tid = threadIdx.x;
    const float bfull_r = bfull[0];

    const int pc = (bid >> 3) & 7;                 // role within group
    const int bA = (bid & 7) * 4 + (bid >> 6);     // batch element (group id)
    int* grpcnt = bar + 576 + bA * 32;

    // phase A consts (jc == pc)
    const int jq = tid & 15, kh = tid >> 4;
    const float bdec_r = (tid < 64) ? bdec[pc * 64 + tid] : 0.f;
    // phase B consts
    const int pl = tid >> 3, ks = tid & 7;
    const int cnt_b = (pc < 4) ? 25 : 24;
    const int p0 = (pc < 4) ? pc * 25 : 100 + (pc - 4) * 24;
    // phase C consts: thread = (d, gate); this block owns d in [pc*64, pc*64+64)
    const int cd = pc * 64 + (tid >> 2);
    const int cgate = tid & 3;
    const int crow = cgate * DEC + cd;
    const float* wi = Wih + (size_t)crow * (EE + ENC) + EE;   // ctx part [512]
    const float* wh = Whh + (size_t)crow * DEC;               // h part   [512]

    // c state lives in a register of the gate-0 lane of each quad
    float creg = (cgate == 0) ? cbuf[bA * DEC + cd] : 0.f;

    // persistent v_att in LDS
    aux[AUX_VS + tid] = vatt[tid];
    aux[AUX_VS + 256 + tid] = vatt[tid + 256];
    __syncthreads();

    for (int st = 0; st < TT; ++st) {
        const float* h_in = hbuf + (size_t)(st & 1) * BB * DEC;
        float* h_out = hbuf + (size_t)((st + 1) & 1) * BB * DEC;

        // ---------- phase A: a[bA][pc*64..+64] = h@Wdec + bdec; zero ctx/Ssum ----------
        {
            float* hs = aux + AUX_HS;
            float* red = aux + AUX_RED;
            {
                float2 hv = aload2(h_in + bA * DEC + 2 * tid);
                hs[2 * tid] = hv.x;
                hs[2 * tid + 1] = hv.y;
            }
            __syncthreads();
            const int j0 = pc * 64 + jq * 4;
            f32x4 a4 = (f32x4){0.f, 0.f, 0.f, 0.f};
            const ushort_t* wp = Wdec + (size_t)(kh * 32) * ATTD + j0;
#pragma unroll 8
            for (int k = 0; k < 32; ++k) {
                uint2 w = *(const uint2*)(wp + (size_t)k * ATTD);
                float hk = hs[kh * 32 + k];
                a4[0] += hk * bf2f((ushort_t)(w.x & 0xffffu));
                a4[1] += hk * bf2f((ushort_t)(w.x >> 16));
                a4[2] += hk * bf2f((ushort_t)(w.y & 0xffffu));
                a4[3] += hk * bf2f((ushort_t)(w.y >> 16));
            }
#pragma unroll
            for (int c = 0; c < 4; ++c) red[(jq * 4 + c) * 17 + kh] = a4[c];
            __syncthreads();
            if (tid < 64) {
                float s = 0.f;
#pragma unroll
                for (int k2 = 0; k2 < 16; ++k2) s += red[tid * 17 + k2];
                astore1(a_glob + bA * ATTD + pc * 64 + tid, s + bdec_r);
                astore1(ctxU + bA * ENC + pc * 64 + tid, 0.f);
                if (pc == 0 && tid == 0) astore1(Ssum + bA, 0.f);
            }
        }
        gbar8(grpcnt, 8 * (3 * st + 1));

        // ---------- phase B: scores -> exp -> atomic ctxU/Ssum (24-25 p's) ----------
        {
            float* as_ = aux + AUX_HS;
            float* vs = aux + AUX_VS;
            float* ep = aux + AUX_EP;
            {
                float2 av = aload2(a_glob + bA * ATTD + 2 * tid);
                as_[2 * tid] = av.x;
                as_[2 * tid + 1] = av.y;
            }
            __syncthreads();
            float acc = 0.f;
            if (pl < cnt_b) {
                const int p = p0 + pl;
                const ushort_t* fr = fp + ((size_t)bA * PP + p) * ATTD + ks * 64;
#pragma unroll 8
                for (int kk = 0; kk < 64; kk += 2) {
                    int kk2 = (kk + 8 * ks) & 63;
                    uint_t fv = *(const uint_t*)(fr + kk2);
                    int k = ks * 64 + kk2;
                    float2 av = *(const float2*)(as_ + k);
                    float2 vv = *(const float2*)(vs + k);
                    acc += ftanh(bf2f((ushort_t)(fv & 0xffffu)) + av.x) * vv.x;
                    acc += ftanh(bf2f((ushort_t)(fv >> 16)) + av.y) * vv.y;
                }
            }
            acc += __shfl_xor(acc, 1);
            acc += __shfl_xor(acc, 2);
            acc += __shfl_xor(acc, 4);
            if (ks == 0) ep[pl] = (pl < cnt_b) ? __expf(acc + bfull_r) : 0.f;
            __syncthreads();
            if (tid < 32) {
                float v = ep[tid];
#pragma unroll
                for (int off = 16; off > 0; off >>= 1) v += __shfl_xor(v, off);
                if (tid == 0) afadd(Ssum + bA, v);
            }
            float c0 = 0.f, c1 = 0.f;
            const ushort_t* fbp = fb + ((size_t)bA * PP + p0) * ENC;
            for (int p2 = 0; p2 < cnt_b; ++p2) {
                float e2 = ep[p2];
                c0 += e2 * bf2f(fbp[(size_t)p2 * ENC + tid]);
                c1 += e2 * bf2f(fbp[(size_t)p2 * ENC + tid + 256]);
            }
            afadd(ctxU + bA * ENC + tid, c0);
            afadd(ctxU + bA * ENC + tid + 256, c1);
        }
        gbar8(grpcnt, 8 * (3 * st + 2));

        // ---------- phase C: this block computes 64 h's of bA (1 thread = 1 gate-row) ----------
        {
            float* xc = aux + AUX_XC;   // [1024] = [ctx_norm | h]
            if (tid == 0) aux[AUX_SS] = aload1(Ssum + bA);
            __syncthreads();
            const float invS = 1.f / aux[AUX_SS];
            {
                float2 cv = aload2(ctxU + bA * ENC + 2 * tid);
                xc[2 * tid] = cv.x * invS;
                xc[2 * tid + 1] = cv.y * invS;
                float2 hv = aload2(h_in + bA * DEC + 2 * tid);
                xc[512 + 2 * tid] = hv.x;
                xc[512 + 2 * tid + 1] = hv.y;
            }
            __syncthreads();

            f32x4 ai = (f32x4){0.f, 0.f, 0.f, 0.f};
            f32x4 ah = (f32x4){0.f, 0.f, 0.f, 0.f};
#pragma unroll 8
            for (int k = 0; k < 512; k += 4) {
                ai += *(const f32x4*)(wi + k) * *(const f32x4*)(xc + k);
                ah += *(const f32x4*)(wh + k) * *(const f32x4*)(xc + 512 + k);
            }
            const size_t trow = (size_t)st * BB + bA;
            float acc = ai[0] + ai[1] + ai[2] + ai[3] + ah[0] + ah[1] + ah[2] + ah[3]
                        + bf2f(gemb[trow * (4 * DEC) + crow]);
            float p1 = __shfl_xor(acc, 1);
            float p2 = __shfl_xor(acc, 2);
            float p3 = __shfl_xor(acc, 3);
            if (cgate == 0) {
                // lane holds i; p1=f, p2=g, p3=o
                float cn = fsig(p1) * creg + fsig(acc) * ftanh(p2);
                float hn = fsig(p3) * ftanh(cn);
                creg = cn;
                astore1(h_out + bA * DEC + cd, hn);
                Hb[trow * DEC + cd] = f2bf(hn);
            }
        }
        gbar8(grpcnt, 8 * (3 * st + 3));
    }
}

// ---------------- launch ----------------

extern "C" void kernel_launch(void* const* d_in, const int* in_sizes, int n_in,
                              void* d_out, int out_size, void* d_ws, size_t ws_size,
                              hipStream_t stream) {
    const float* features  = (const float*)d_in[0];
    const int*   captions  = (const int*)d_in[1];
    const float* emb       = (const float*)d_in[2];
    const float* W_enc_att = (const float*)d_in[3];
    const float* b_enc_att = (const float*)d_in[4];
    const float* W_dec_att = (const float*)d_in[5];
    const float* b_dec_att = (const float*)d_in[6];
    const float* v_att     = (const float*)d_in[7];
    const float* b_full    = (const float*)d_in[8];
    const float* W_init_h  = (const float*)d_in[9];
    const float* b_init_h  = (const float*)d_in[10];
    const float* W_init_c  = (const float*)d_in[11];
    const float* b_init_c  = (const float*)d_in[12];
    const float* W_ih      = (const float*)d_in[13];
    const float* W_hh      = (const float*)d_in[14];
    const float* b_ih      = (const float*)d_in[15];
    const float* b_hh      = (const float*)d_in[16];
    const float* W_fcn     = (const float*)d_in[17];
    const float* b_fcn     = (const float*)d_in[18];
    float* out = (float*)d_out;
    char* ws = (char*)d_ws;

    size_t o = 0;
    ushort_t* Wfcn_b  = (ushort_t*)(ws + o); o += (size_t)DEC * VV * 2;
    ushort_t* Wenc_b  = (ushort_t*)(ws + o); o += (size_t)ENC * ATTD * 2;
    ushort_t* Wdec_b  = (ushort_t*)(ws + o); o += (size_t)DEC * ATTD * 2;
    ushort_t* fb      = (ushort_t*)(ws + o); o += (size_t)BB * PP * ENC * 2;
    ushort_t* fp_b    = (ushort_t*)(ws + o); o += (size_t)BB * PP * ATTD * 2;
    ushort_t* emb_bf  = (ushort_t*)(ws + o); o += (size_t)TT * BB * EE * 2;
    ushort_t* WihT    = (ushort_t*)(ws + o); o += (size_t)EE * 4 * DEC * 2;
    ushort_t* gembuf  = (ushort_t*)(ws + o); o += (size_t)TT * BB * 4 * DEC * 2;
    float*    bsum    = (float*)(ws + o);    o += (size_t)4 * DEC * 4;
    ushort_t* Hb      = (ushort_t*)(ws + o); o += (size_t)TT * BB * DEC * 2;
    float*    hbuf    = (float*)(ws + o);    o += (size_t)2 * BB * DEC * 4;
    float*    cbuf    = (float*)(ws + o);    o += (size_t)BB * DEC * 4;
    float*    a_glob  = (float*)(ws + o);    o += (size_t)BB * ATTD * 4;
    float*    ctxU    = (float*)(ws + o);    o += (size_t)BB * ENC * 4;
    float*    Ssum    = (float*)(ws + o);    o += (size_t)BB * 4 + 64;
    int*      bar     = (int*)(ws + o);      o += 4096 * 4;   // 16 KB barrier state

    // prep
    k_cvt<<<2048, 256, 0, stream>>>(W_fcn, Wfcn_b, DEC * VV);
    k_cvt<<<256, 256, 0, stream>>>(W_enc_att, Wenc_b, ENC * ATTD);
    k_cvt<<<256, 256, 0, stream>>>(W_dec_att, Wdec_b, DEC * ATTD);
    k_cvt<<<2048, 256, 0, stream>>>(features, fb, BB * PP * ENC);
    k_embed_bf<<<1024, 256, 0, stream>>>(captions, emb, emb_bf);
    k_cvtT<<<1024, 256, 0, stream>>>(W_ih, WihT);
    k_bsum<<<8, 256, 0, stream>>>(b_ih, b_hh, bsum, 4 * DEC);
    k_init<<<32, 256, 0, stream>>>(features, W_init_h, b_init_h, W_init_c, b_init_c,
                                   hbuf, cbuf, bar);
    // feat_proj = features @ W_enc_att + b_enc_att (bf16)
    k_gemm<0><<<dim3((BB * PP) / 128, ATTD / 128), 256, 0, stream>>>(
        fb, Wenc_b, b_enc_att, fp_b, nullptr, BB * PP, ATTD, ENC);
    // gates_emb = embeds @ W_ih[:, :256]^T + (b_ih + b_hh)  (bf16)
    k_gemm<0><<<dim3((TT * BB + 127) / 128, (4 * DEC) / 128), 256, 0, stream>>>(
        emb_bf, WihT, bsum, gembuf, nullptr, TT * BB, 4 * DEC, EE);

    // persistent recurrent kernel: all 127 steps, group-local sync only
    k_steps<<<NBLK, 256, 0, stream>>>(fp_b, fb, Wdec_b, b_dec_att, v_att, b_full,
                                      W_ih, W_hh, gembuf, hbuf, cbuf,
                                      a_glob, ctxU, Ssum, Hb, bar);

    // out = H @ W_fcn + b_fcn, scattered to [b][t][v]
    k_gemm<1><<<dim3((TT * BB + 127) / 128, (VV + 127) / 128), 256, 0, stream>>>(
        Hb, Wfcn_b, b_fcn, nullptr, out, TT * BB, VV, DEC);
}

// Round 8
// 5093.311 us; speedup vs baseline: 2.9256x; 1.2013x over previous
//
#include <hip/hip_runtime.h>
#include <hip/hip_bf16.h>
#include <stdint.h>

#define BB 32
#define PP 196
#define ENC 512
#define DEC 512
#define ATTD 512
#define EE 256
#define SS 128
#define VV 10000
#define TT 127    // S-1 steps
#define NBLK 256

typedef unsigned short ushort_t;
typedef unsigned int uint_t;
typedef unsigned long long u64_t;
typedef float f32x4 __attribute__((ext_vector_type(4)));
typedef short s16x8 __attribute__((ext_vector_type(8)));

__device__ __forceinline__ float bf2f(ushort_t u) {
    uint_t x = ((uint_t)u) << 16;
    return __uint_as_float(x);
}
// decode a packed pair of bf16 in one uint: lo -> u<<16, hi -> u & 0xffff0000
__device__ __forceinline__ float bflo(uint_t u) { return __uint_as_float(u << 16); }
__device__ __forceinline__ float bfhi(uint_t u) { return __uint_as_float(u & 0xffff0000u); }
__device__ __forceinline__ ushort_t f2bf(float f) {
    uint_t u = __float_as_uint(f);
    uint_t r = (u + 0x7FFFu + ((u >> 16) & 1u)) >> 16;
    return (ushort_t)r;
}
__device__ __forceinline__ float ftanh(float x) {
    x = fminf(15.f, fmaxf(-15.f, x));
    float e = __expf(2.f * x);
    return (e - 1.f) / (e + 1.f);
}
__device__ __forceinline__ float fsig(float x) {
    return 1.f / (1.f + __expf(-x));
}

// ---- coherence helpers: agent-scope relaxed atomics (live at LLC) ----
__device__ __forceinline__ float aload1(const float* p) {
    return __hip_atomic_load(p, __ATOMIC_RELAXED, __HIP_MEMORY_SCOPE_AGENT);
}
__device__ __forceinline__ void astore1(float* p, float v) {
    __hip_atomic_store(p, v, __ATOMIC_RELAXED, __HIP_MEMORY_SCOPE_AGENT);
}
__device__ __forceinline__ float2 aload2(const float* p) {
    u64_t v = __hip_atomic_load((const u64_t*)p, __ATOMIC_RELAXED, __HIP_MEMORY_SCOPE_AGENT);
    float2 r;
    r.x = __uint_as_float((uint_t)v);
    r.y = __uint_as_float((uint_t)(v >> 32));
    return r;
}

// ---------------- prep kernels ----------------

__global__ void k_cvt(const float* __restrict__ s, ushort_t* __restrict__ d, int n) {
    for (int i = blockIdx.x * blockDim.x + threadIdx.x; i < n; i += gridDim.x * blockDim.x)
        d[i] = f2bf(s[i]);
}

__global__ void k_embed_bf(const int* __restrict__ cap, const float* __restrict__ emb,
                           ushort_t* __restrict__ out) {
    const int n = TT * BB * EE;
    for (int i = blockIdx.x * blockDim.x + threadIdx.x; i < n; i += gridDim.x * blockDim.x) {
        int e = i & (EE - 1);
        int b = (i >> 8) & (BB - 1);
        int t = i >> 13;
        int tok = cap[b * SS + t];
        out[i] = f2bf(emb[(size_t)tok * EE + e]);
    }
}

__global__ void k_cvtT(const float* __restrict__ Wih, ushort_t* __restrict__ out) {
    const int n = EE * 4 * DEC;
    for (int i = blockIdx.x * blockDim.x + threadIdx.x; i < n; i += gridDim.x * blockDim.x) {
        int k = i & (EE - 1);
        int row = i >> 8;
        out[(size_t)k * (4 * DEC) + row] = f2bf(Wih[(size_t)row * (EE + ENC) + k]);
    }
}

// gate weights, bf16, interleaved for coalesced per-row reads:
// out[((kc*2048) + pc*256 + t)*8 + j] = W(row(pc,t), k=kc*8+j)
// where row(pc,t) = (t&3)*512 + pc*64 + (t>>2); W(row,k) = k<512 ? Wih[row][256+k] : Whh[row][k-512]
__global__ void k_cvtG(const float* __restrict__ Wih, const float* __restrict__ Whh,
                       ushort_t* __restrict__ out) {
    const int n = 4 * DEC * 1024;   // 2,097,152
    for (int i = blockIdx.x * blockDim.x + threadIdx.x; i < n; i += gridDim.x * blockDim.x) {
        int j = i & 7;
        int rp = (i >> 3) & 2047;   // pc*256 + t
        int kc = i >> 14;
        int pc = rp >> 8, t = rp & 255;
        int row = (t & 3) * 512 + pc * 64 + (t >> 2);
        int k = kc * 8 + j;
        float v = (k < 512) ? Wih[(size_t)row * (EE + ENC) + EE + k]
                            : Whh[(size_t)row * DEC + (k - 512)];
        out[i] = f2bf(v);
    }
}

__global__ void k_bsum(const float* __restrict__ a, const float* __restrict__ b,
                       float* __restrict__ o, int n) {
    int i = blockIdx.x * blockDim.x + threadIdx.x;
    if (i < n) o[i] = a[i] + b[i];
}

// per-b: mean over P, then h0/c0; block 0 zeroes all barrier state
__global__ __launch_bounds__(256) void k_init(const float* __restrict__ feat,
                                              const float* __restrict__ Wh, const float* __restrict__ bh,
                                              const float* __restrict__ Wc, const float* __restrict__ bc,
                                              float* __restrict__ h0, float* __restrict__ c0,
                                              int* __restrict__ bar) {
    __shared__ float ms[ENC];
    int b = blockIdx.x, t = threadIdx.x;
    if (b == 0) {
        for (int i = t; i < 4096; i += 256) bar[i] = 0;
    }
    for (int c = t; c < ENC; c += 256) {
        float s = 0.f;
        for (int p = 0; p < PP; ++p) s += feat[((size_t)b * PP + p) * ENC + c];
        ms[c] = s * (1.f / (float)PP);
    }
    __syncthreads();
    int d0 = 2 * t;
    float ah0 = 0.f, ah1 = 0.f, ac0 = 0.f, ac1 = 0.f;
    for (int k = 0; k < ENC; ++k) {
        float mk = ms[k];
        float2 wh = *(const float2*)(Wh + (size_t)k * DEC + d0);
        float2 wc = *(const float2*)(Wc + (size_t)k * DEC + d0);
        ah0 += mk * wh.x; ah1 += mk * wh.y;
        ac0 += mk * wc.x; ac1 += mk * wc.y;
    }
    h0[b * DEC + d0] = ah0 + bh[d0];
    h0[b * DEC + d0 + 1] = ah1 + bh[d0 + 1];
    c0[b * DEC + d0] = ac0 + bc[d0];
    c0[b * DEC + d0 + 1] = ac1 + bc[d0 + 1];
}

// ---------------- bf16 MFMA GEMM (128x128 tile, BK=32, 4 waves) ----------------
template <int MODE>
__global__ __launch_bounds__(256) void k_gemm(const ushort_t* __restrict__ A,
                                              const ushort_t* __restrict__ Bm,
                                              const float* __restrict__ bias,
                                              ushort_t* __restrict__ outb,
                                              float* __restrict__ outf,
                                              int M, int N, int K) {
    __shared__ __align__(16) ushort_t As[128 * 32];
    __shared__ __align__(16) ushort_t Bs[128 * 32];

    const int tid = threadIdx.x;
    const int wid = tid >> 6, lane = tid & 63;
    const int wm = wid >> 1, wn = wid & 1;
    const int lr = lane & 15, lk = (lane >> 4) * 8;
    const int row0 = blockIdx.x * 128, col0 = blockIdx.y * 128;

    f32x4 acc[4][4];
#pragma unroll
    for (int i = 0; i < 4; ++i)
#pragma unroll
        for (int j = 0; j < 4; ++j) acc[i][j] = (f32x4){0.f, 0.f, 0.f, 0.f};

    for (int k0 = 0; k0 < K; k0 += 32) {
        {
            int r = tid >> 1, kk = (tid & 1) * 16;
            int gr = row0 + r;
            uint4 v0 = {0, 0, 0, 0}, v1 = {0, 0, 0, 0};
            if (gr < M) {
                const ushort_t* sp = A + (size_t)gr * K + k0 + kk;
                v0 = *(const uint4*)sp;
                v1 = *(const uint4*)(sp + 8);
            }
            *(uint4*)(As + r * 32 + kk) = v0;
            *(uint4*)(As + r * 32 + kk + 8) = v1;
        }
        {
            int kk = tid >> 3;
            int n = (tid & 7) * 16;
            const ushort_t* sp = Bm + (size_t)(k0 + kk) * N + col0 + n;
            ushort_t tmp[16];
            if (col0 + n + 16 <= N) {
                *(uint4*)tmp = *(const uint4*)sp;
                *(uint4*)(tmp + 8) = *(const uint4*)(sp + 8);
            } else {
#pragma unroll
                for (int j = 0; j < 16; ++j) {
                    int c = col0 + n + j;
                    tmp[j] = (c < N) ? sp[j] : (ushort_t)0;
                }
            }
#pragma unroll
            for (int j = 0; j < 16; ++j) Bs[(n + j) * 32 + kk] = tmp[j];
        }
        __syncthreads();
        s16x8 af[4], bfr[4];
#pragma unroll
        for (int i = 0; i < 4; ++i)
            af[i] = *(const s16x8*)(As + (wm * 64 + i * 16 + lr) * 32 + lk);
#pragma unroll
        for (int j = 0; j < 4; ++j)
            bfr[j] = *(const s16x8*)(Bs + (wn * 64 + j * 16 + lr) * 32 + lk);
#pragma unroll
        for (int i = 0; i < 4; ++i)
#pragma unroll
            for (int j = 0; j < 4; ++j)
                acc[i][j] = __builtin_amdgcn_mfma_f32_16x16x32_bf16(af[i], bfr[j], acc[i][j], 0, 0, 0);
        __syncthreads();
    }

    const int lrow = (lane >> 4) * 4;
#pragma unroll
    for (int i = 0; i < 4; ++i) {
#pragma unroll
        for (int j = 0; j < 4; ++j) {
            int gr0 = row0 + wm * 64 + i * 16 + lrow;
            int gc = col0 + wn * 64 + j * 16 + lr;
#pragma unroll
            for (int r = 0; r < 4; ++r) {
                int gr = gr0 + r;
                if (gr < M && gc < N) {
                    float v = acc[i][j][r] + bias[gc];
                    if (MODE == 0) {
                        outb[(size_t)gr * N + gc] = f2bf(v);
                    } else {
                        int t = gr >> 5, b = gr & 31;
                        outf[((size_t)(b * TT + t)) * VV + gc] = v;
                    }
                }
            }
        }
    }
}

// ---------------- persistent recurrent kernel ----------------
// 256 blocks. Role decode designed so each XCD (bid%8 heuristic) hosts only
// 4 pc-slices x 8 bA's -> per-XCD unique working set ~4MB (fits L2):
//   q = bid&7, r = bid>>3;  pc = (4q + (r&3)) & 7;  bA = (r>>2) + 8*(q>>1)
// Per step: [phase AB: block-local redundant a + p-sliced scores + partial ctx
// (plain stores, NO atomics)] -> 8-way bar -> [phase C: sum partials + gate
// GEMV (bf16 interleaved weights) + LSTM pointwise, c in register] -> bar.

__device__ __forceinline__ void gbar8(int* cnt, int target) {
    asm volatile("s_waitcnt vmcnt(0)" ::: "memory");   // drain stores to LLC
    __syncthreads();
    if (threadIdx.x == 0) {
        __hip_atomic_fetch_add(cnt, 1, __ATOMIC_RELAXED, __HIP_MEMORY_SCOPE_AGENT);
        while (__hip_atomic_load(cnt, __ATOMIC_RELAXED, __HIP_MEMORY_SCOPE_AGENT) < target)
            __builtin_amdgcn_s_sleep(1);
    }
    __syncthreads();
}

__global__ __launch_bounds__(256) void k_steps(
    const ushort_t* __restrict__ fp, const ushort_t* __restrict__ fb,
    const ushort_t* __restrict__ Wdec, const float* __restrict__ bdec,
    const float* __restrict__ vatt, const float* __restrict__ bfull,
    const ushort_t* __restrict__ Wg, const ushort_t* __restrict__ gemb,
    float* __restrict__ hbuf, const float* __restrict__ cbuf,
    float* __restrict__ ctxP, float* __restrict__ Sp,
    ushort_t* __restrict__ Hb, int* __restrict__ bar) {

    __shared__ __align__(16) float hs[512];   // h_in[bA]
    __shared__ __align__(16) float as_[512];  // a vector
    __shared__ __align__(16) float vs[512];   // persistent v_att
    __shared__ __align__(16) float cs[512];   // normalized ctx (phase C)
    __shared__ float ep[32];
    __shared__ float sS[1];

    const int bid = blockIdx.x, tid = threadIdx.x;
    const float bfull_r = bfull[0];

    const int q = bid & 7, r = bid >> 3;
    const int pc = (4 * q + (r & 3)) & 7;
    const int bA = (r >> 2) + 8 * (q >> 1);
    int* grpcnt = bar + 576 + bA * 32;

    // phase B consts
    const int pl = tid >> 3, ks = tid & 7;
    const int cnt_b = (pc < 4) ? 25 : 24;
    const int p0 = (pc < 4) ? pc * 25 : 100 + (pc - 4) * 24;
    // phase A bias (cols 2t, 2t+1)
    const float bd0 = bdec[2 * tid], bd1 = bdec[2 * tid + 1];
    // phase C consts: thread t -> gate = t&3, d = pc*64 + (t>>2)
    const int cgate = tid & 3;
    const int cd = pc * 64 + (tid >> 2);
    const int crow = cgate * DEC + cd;
    float creg = (cgate == 0) ? cbuf[bA * DEC + cd] : 0.f;

    vs[tid] = vatt[tid];
    vs[tid + 256] = vatt[tid + 256];
    __syncthreads();

    for (int st = 0; st < TT; ++st) {
        const float* h_in = hbuf + (size_t)(st & 1) * BB * DEC;
        float* h_out = hbuf + (size_t)((st + 1) & 1) * BB * DEC;

        // ---------- phase AB (block-local) ----------
        {
            float2 hv = aload2(h_in + bA * DEC + 2 * tid);
            hs[2 * tid] = hv.x;
            hs[2 * tid + 1] = hv.y;
        }
        __syncthreads();
        // redundant a: thread -> cols 2t, 2t+1; Wdec is [k][512] bf16
        {
            float a0 = 0.f, a1 = 0.f;
            const ushort_t* wp = Wdec + 2 * tid;
#pragma unroll 8
            for (int k = 0; k < DEC; ++k) {
                uint_t w = *(const uint_t*)(wp + (size_t)k * ATTD);
                float hk = hs[k];
                a0 += hk * bflo(w);
                a1 += hk * bfhi(w);
            }
            as_[2 * tid] = a0 + bd0;
            as_[2 * tid + 1] = a1 + bd1;
        }
        __syncthreads();
        // sliced scores: (pl, ks) over this block's 24-25 p's
        {
            float acc = 0.f;
            if (pl < cnt_b) {
                const int p = p0 + pl;
                const ushort_t* fr = fp + ((size_t)bA * PP + p) * ATTD + ks * 64;
#pragma unroll 8
                for (int kk = 0; kk < 64; kk += 2) {
                    int kk2 = (kk + 8 * ks) & 63;
                    uint_t fv = *(const uint_t*)(fr + kk2);
                    int k = ks * 64 + kk2;
                    float2 av = *(const float2*)(as_ + k);
                    float2 vv = *(const float2*)(vs + k);
                    acc += ftanh(bflo(fv) + av.x) * vv.x;
                    acc += ftanh(bfhi(fv) + av.y) * vv.y;
                }
            }
            acc += __shfl_xor(acc, 1);
            acc += __shfl_xor(acc, 2);
            acc += __shfl_xor(acc, 4);
            if (ks == 0) ep[pl] = (pl < cnt_b) ? __expf(acc + bfull_r) : 0.f;
        }
        __syncthreads();
        // partial S + partial ctx -> private buffers (plain agent stores)
        {
            if (tid < 32) {
                float v = ep[tid];
#pragma unroll
                for (int off = 16; off > 0; off >>= 1) v += __shfl_xor(v, off);
                if (tid == 0) astore1(Sp + bA * 8 + pc, v);
            }
            float c0 = 0.f, c1 = 0.f;
            const ushort_t* fbp = fb + ((size_t)bA * PP + p0) * ENC;
            for (int p2 = 0; p2 < cnt_b; ++p2) {
                float e2 = ep[p2];
                c0 += e2 * bf2f(fbp[(size_t)p2 * ENC + tid]);
                c1 += e2 * bf2f(fbp[(size_t)p2 * ENC + tid + 256]);
            }
            float* cp = ctxP + ((size_t)bA * 8 + pc) * 512;
            astore1(cp + tid, c0);
            astore1(cp + tid + 256, c1);
        }
        gbar8(grpcnt, 8 * (2 * st + 1));

        // ---------- phase C: sum partials, gate GEMV, LSTM pointwise ----------
        {
            if (tid < 8) {
                float s = aload1(Sp + bA * 8 + tid);
                s += __shfl_xor(s, 1);
                s += __shfl_xor(s, 2);
                s += __shfl_xor(s, 4);
                if (tid == 0) sS[0] = s;
            }
            __syncthreads();
            const float invS = 1.f / sS[0];
            {
                float s0 = 0.f, s1 = 0.f;
                const float* cp = ctxP + (size_t)bA * 8 * 512 + 2 * tid;
#pragma unroll
                for (int pc2 = 0; pc2 < 8; ++pc2) {
                    float2 v = aload2(cp + pc2 * 512);
                    s0 += v.x;
                    s1 += v.y;
                }
                cs[2 * tid] = s0 * invS;
                cs[2 * tid + 1] = s1 * invS;
            }
            __syncthreads();

            // gate dot: row' = pc*256 + tid, K=1024 (ctx | h), bf16 interleaved
            float acc = 0.f;
            const ushort_t* wrow = Wg + ((size_t)pc * 256 + tid) * 8;
#pragma unroll 4
            for (int kc = 0; kc < 64; ++kc) {
                uint4 wv = *(const uint4*)(wrow + (size_t)kc * 2048 * 8);
                const float* x = cs + kc * 8;
                acc += bflo(wv.x) * x[0] + bfhi(wv.x) * x[1];
                acc += bflo(wv.y) * x[2] + bfhi(wv.y) * x[3];
                acc += bflo(wv.z) * x[4] + bfhi(wv.z) * x[5];
                acc += bflo(wv.w) * x[6] + bfhi(wv.w) * x[7];
            }
#pragma unroll 4
            for (int kc = 64; kc < 128; ++kc) {
                uint4 wv = *(const uint4*)(wrow + (size_t)kc * 2048 * 8);
                const float* x = hs + (kc - 64) * 8;
                acc += bflo(wv.x) * x[0] + bfhi(wv.x) * x[1];
                acc += bflo(wv.y) * x[2] + bfhi(wv.y) * x[3];
                acc += bflo(wv.z) * x[4] + bfhi(wv.z) * x[5];
                acc += bflo(wv.w) * x[6] + bfhi(wv.w) * x[7];
            }
            const size_t trow = (size_t)st * BB + bA;
            acc += bf2f(gemb[trow * (4 * DEC) + crow]);
            float p1 = __shfl_xor(acc, 1);
            float p2 = __shfl_xor(acc, 2);
            float p3 = __shfl_xor(acc, 3);
            if (cgate == 0) {
                // lane gate0 holds i; p1=f, p2=g, p3=o
                float cn = fsig(p1) * creg + fsig(acc) * ftanh(p2);
                float hn = fsig(p3) * ftanh(cn);
                creg = cn;
                astore1(h_out + bA * DEC + cd, hn);
                Hb[trow * DEC + cd] = f2bf(hn);
            }
        }
        gbar8(grpcnt, 8 * (2 * st + 2));
    }
}

// ---------------- launch ----------------

extern "C" void kernel_launch(void* const* d_in, const int* in_sizes, int n_in,
                              void* d_out, int out_size, void* d_ws, size_t ws_size,
                              hipStream_t stream) {
    const float* features  = (const float*)d_in[0];
    const int*   captions  = (const int*)d_in[1];
    const float* emb       = (const float*)d_in[2];
    const float* W_enc_att = (const float*)d_in[3];
    const float* b_enc_att = (const float*)d_in[4];
    const float* W_dec_att = (const float*)d_in[5];
    const float* b_dec_att = (const float*)d_in[6];
    const float* v_att     = (const float*)d_in[7];
    const float* b_full    = (const float*)d_in[8];
    const float* W_init_h  = (const float*)d_in[9];
    const float* b_init_h  = (const float*)d_in[10];
    const float* W_init_c  = (const float*)d_in[11];
    const float* b_init_c  = (const float*)d_in[12];
    const float* W_ih      = (const float*)d_in[13];
    const float* W_hh      = (const float*)d_in[14];
    const float* b_ih      = (const float*)d_in[15];
    const float* b_hh      = (const float*)d_in[16];
    const float* W_fcn     = (const float*)d_in[17];
    const float* b_fcn     = (const float*)d_in[18];
    float* out = (float*)d_out;
    char* ws = (char*)d_ws;

    size_t o = 0;
    ushort_t* Wfcn_b  = (ushort_t*)(ws + o); o += (size_t)DEC * VV * 2;
    ushort_t* Wenc_b  = (ushort_t*)(ws + o); o += (size_t)ENC * ATTD * 2;
    ushort_t* Wdec_b  = (ushort_t*)(ws + o); o += (size_t)DEC * ATTD * 2;
    ushort_t* fb      = (ushort_t*)(ws + o); o += (size_t)BB * PP * ENC * 2;
    ushort_t* fp_b    = (ushort_t*)(ws + o); o += (size_t)BB * PP * ATTD * 2;
    ushort_t* emb_bf  = (ushort_t*)(ws + o); o += (size_t)TT * BB * EE * 2;
    ushort_t* WihT    = (ushort_t*)(ws + o); o += (size_t)EE * 4 * DEC * 2;
    ushort_t* gembuf  = (ushort_t*)(ws + o); o += (size_t)TT * BB * 4 * DEC * 2;
    ushort_t* Wg      = (ushort_t*)(ws + o); o += (size_t)4 * DEC * 1024 * 2;  // 4 MB
    float*    bsum    = (float*)(ws + o);    o += (size_t)4 * DEC * 4;
    ushort_t* Hb      = (ushort_t*)(ws + o); o += (size_t)TT * BB * DEC * 2;
    float*    hbuf    = (float*)(ws + o);    o += (size_t)2 * BB * DEC * 4;
    float*    cbuf    = (float*)(ws + o);    o += (size_t)BB * DEC * 4;
    float*    ctxP    = (float*)(ws + o);    o += (size_t)BB * 8 * 512 * 4;    // 512 KB
    float*    Sp      = (float*)(ws + o);    o += (size_t)BB * 8 * 4 + 64;
    int*      bar     = (int*)(ws + o);      o += 4096 * 4;

    // prep
    k_cvt<<<2048, 256, 0, stream>>>(W_fcn, Wfcn_b, DEC * VV);
    k_cvt<<<256, 256, 0, stream>>>(W_enc_att, Wenc_b, ENC * ATTD);
    k_cvt<<<256, 256, 0, stream>>>(W_dec_att, Wdec_b, DEC * ATTD);
    k_cvt<<<2048, 256, 0, stream>>>(features, fb, BB * PP * ENC);
    k_embed_bf<<<1024, 256, 0, stream>>>(captions, emb, emb_bf);
    k_cvtT<<<1024, 256, 0, stream>>>(W_ih, WihT);
    k_cvtG<<<4096, 256, 0, stream>>>(W_ih, W_hh, Wg);
    k_bsum<<<8, 256, 0, stream>>>(b_ih, b_hh, bsum, 4 * DEC);
    k_init<<<32, 256, 0, stream>>>(features, W_init_h, b_init_h, W_init_c, b_init_c,
                                   hbuf, cbuf, bar);
    // feat_proj = features @ W_enc_att + b_enc_att (bf16)
    k_gemm<0><<<dim3((BB * PP) / 128, ATTD / 128), 256, 0, stream>>>(
        fb, Wenc_b, b_enc_att, fp_b, nullptr, BB * PP, ATTD, ENC);
    // gates_emb = embeds @ W_ih[:, :256]^T + (b_ih + b_hh)  (bf16)
    k_gemm<0><<<dim3((TT * BB + 127) / 128, (4 * DEC) / 128), 256, 0, stream>>>(
        emb_bf, WihT, bsum, gembuf, nullptr, TT * BB, 4 * DEC, EE);

    // persistent recurrent kernel: 2 group-local barriers/step, no data atomics
    k_steps<<<NBLK, 256, 0, stream>>>(fp_b, fb, Wdec_b, b_dec_att, v_att, b_full,
                                      Wg, gembuf, hbuf, cbuf,
                                      ctxP, Sp, Hb, bar);

    // out = H @ W_fcn + b_fcn, scattered to [b][t][v]
    k_gemm<1><<<dim3((TT * BB + 127) / 128, (VV + 127) / 128), 256, 0, stream>>>(
        Hb, Wfcn_b, b_fcn, nullptr, out, TT * BB, VV, DEC);
}

// Round 9
// 2786.126 us; speedup vs baseline: 5.3483x; 1.8281x over previous
//
#include <hip/hip_runtime.h>
#include <hip/hip_bf16.h>
#include <stdint.h>

#define BB 32
#define PP 196
#define ENC 512
#define DEC 512
#define ATTD 512
#define EE 256
#define SS 128
#define VV 10000
#define TT 127    // S-1 steps
#define NBLK 512

typedef unsigned short ushort_t;
typedef unsigned int uint_t;
typedef unsigned long long u64_t;
typedef float f32x4 __attribute__((ext_vector_type(4)));
typedef short s16x8 __attribute__((ext_vector_type(8)));

__device__ __forceinline__ float bf2f(ushort_t u) {
    uint_t x = ((uint_t)u) << 16;
    return __uint_as_float(x);
}
__device__ __forceinline__ float bflo(uint_t u) { return __uint_as_float(u << 16); }
__device__ __forceinline__ float bfhi(uint_t u) { return __uint_as_float(u & 0xffff0000u); }
__device__ __forceinline__ ushort_t f2bf(float f) {
    uint_t u = __float_as_uint(f);
    uint_t r = (u + 0x7FFFu + ((u >> 16) & 1u)) >> 16;
    return (ushort_t)r;
}
__device__ __forceinline__ float ftanh(float x) {
    x = fminf(15.f, fmaxf(-15.f, x));
    float e = __expf(2.f * x);
    return (e - 1.f) / (e + 1.f);
}
__device__ __forceinline__ float fsig(float x) {
    return 1.f / (1.f + __expf(-x));
}

// ---- coherence helpers: agent-scope relaxed atomics (live at LLC) ----
__device__ __forceinline__ float aload1(const float* p) {
    return __hip_atomic_load(p, __ATOMIC_RELAXED, __HIP_MEMORY_SCOPE_AGENT);
}
__device__ __forceinline__ void astore1(float* p, float v) {
    __hip_atomic_store(p, v, __ATOMIC_RELAXED, __HIP_MEMORY_SCOPE_AGENT);
}
__device__ __forceinline__ float2 aload2(const float* p) {
    u64_t v = __hip_atomic_load((const u64_t*)p, __ATOMIC_RELAXED, __HIP_MEMORY_SCOPE_AGENT);
    float2 r;
    r.x = __uint_as_float((uint_t)v);
    r.y = __uint_as_float((uint_t)(v >> 32));
    return r;
}

// ---------------- prep kernels ----------------

__global__ void k_cvt(const float* __restrict__ s, ushort_t* __restrict__ d, int n) {
    for (int i = blockIdx.x * blockDim.x + threadIdx.x; i < n; i += gridDim.x * blockDim.x)
        d[i] = f2bf(s[i]);
}

// WdecT[j][k] = bf16(W_dec_att[k][j])
__global__ void k_cvtD(const float* __restrict__ Wdec, ushort_t* __restrict__ out) {
    const int n = DEC * ATTD;
    for (int i = blockIdx.x * blockDim.x + threadIdx.x; i < n; i += gridDim.x * blockDim.x) {
        int k = i & (ATTD - 1);
        int j = i >> 9;
        out[i] = f2bf(Wdec[(size_t)k * ATTD + j]);
    }
}

__global__ void k_embed_bf(const int* __restrict__ cap, const float* __restrict__ emb,
                           ushort_t* __restrict__ out) {
    const int n = TT * BB * EE;
    for (int i = blockIdx.x * blockDim.x + threadIdx.x; i < n; i += gridDim.x * blockDim.x) {
        int e = i & (EE - 1);
        int b = (i >> 8) & (BB - 1);
        int t = i >> 13;
        int tok = cap[b * SS + t];
        out[i] = f2bf(emb[(size_t)tok * EE + e]);
    }
}

__global__ void k_cvtT(const float* __restrict__ Wih, ushort_t* __restrict__ out) {
    const int n = EE * 4 * DEC;
    for (int i = blockIdx.x * blockDim.x + threadIdx.x; i < n; i += gridDim.x * blockDim.x) {
        int k = i & (EE - 1);
        int row = i >> 8;
        out[(size_t)k * (4 * DEC) + row] = f2bf(Wih[(size_t)row * (EE + ENC) + k]);
    }
}

// gate weights bf16, layout [pcg][kh][kc][R][8]:
// R = d_local*4 + gate encodes (d = pcg*32+d_local, crow = gate*512+d), k = kh*512 + kc*8 + j
__global__ void k_cvtG2(const float* __restrict__ Wih, const float* __restrict__ Whh,
                        ushort_t* __restrict__ out) {
    const int n = 16 * 2 * 64 * 128 * 8;   // 2,097,152
    for (int i = blockIdx.x * blockDim.x + threadIdx.x; i < n; i += gridDim.x * blockDim.x) {
        int j = i & 7;
        int R = (i >> 3) & 127;
        int kc = (i >> 10) & 63;
        int kh = (i >> 16) & 1;
        int pcg = i >> 17;
        int d = pcg * 32 + (R >> 2);
        int gate = R & 3;
        int row = gate * DEC + d;
        int k = kh * 512 + kc * 8 + j;
        float v = (k < 512) ? Wih[(size_t)row * (EE + ENC) + EE + k]
                            : Whh[(size_t)row * DEC + (k - 512)];
        out[i] = f2bf(v);
    }
}

__global__ void k_bsum(const float* __restrict__ a, const float* __restrict__ b,
                       float* __restrict__ o, int n) {
    int i = blockIdx.x * blockDim.x + threadIdx.x;
    if (i < n) o[i] = a[i] + b[i];
}

// per-b: mean over P, then h0/c0; block 0 zeroes all barrier state
__global__ __launch_bounds__(256) void k_init(const float* __restrict__ feat,
                                              const float* __restrict__ Wh, const float* __restrict__ bh,
                                              const float* __restrict__ Wc, const float* __restrict__ bc,
                                              float* __restrict__ h0, float* __restrict__ c0,
                                              int* __restrict__ bar) {
    __shared__ float ms[ENC];
    int b = blockIdx.x, t = threadIdx.x;
    if (b == 0) {
        for (int i = t; i < 4096; i += 256) bar[i] = 0;
    }
    for (int c = t; c < ENC; c += 256) {
        float s = 0.f;
        for (int p = 0; p < PP; ++p) s += feat[((size_t)b * PP + p) * ENC + c];
        ms[c] = s * (1.f / (float)PP);
    }
    __syncthreads();
    int d0 = 2 * t;
    float ah0 = 0.f, ah1 = 0.f, ac0 = 0.f, ac1 = 0.f;
    for (int k = 0; k < ENC; ++k) {
        float mk = ms[k];
        float2 wh = *(const float2*)(Wh + (size_t)k * DEC + d0);
        float2 wc = *(const float2*)(Wc + (size_t)k * DEC + d0);
        ah0 += mk * wh.x; ah1 += mk * wh.y;
        ac0 += mk * wc.x; ac1 += mk * wc.y;
    }
    h0[b * DEC + d0] = ah0 + bh[d0];
    h0[b * DEC + d0 + 1] = ah1 + bh[d0 + 1];
    c0[b * DEC + d0] = ac0 + bc[d0];
    c0[b * DEC + d0 + 1] = ac1 + bc[d0 + 1];
}

// ---------------- bf16 MFMA GEMM (128x128 tile, BK=32, 4 waves) ----------------
template <int MODE>
__global__ __launch_bounds__(256) void k_gemm(const ushort_t* __restrict__ A,
                                              const ushort_t* __restrict__ Bm,
                                              const float* __restrict__ bias,
                                              ushort_t* __restrict__ outb,
                                              float* __restrict__ outf,
                                              int M, int N, int K) {
    __shared__ __align__(16) ushort_t As[128 * 32];
    __shared__ __align__(16) ushort_t Bs[128 * 32];

    const int tid = threadIdx.x;
    const int wid = tid >> 6, lane = tid & 63;
    const int wm = wid >> 1, wn = wid & 1;
    const int lr = lane & 15, lk = (lane >> 4) * 8;
    const int row0 = blockIdx.x * 128, col0 = blockIdx.y * 128;

    f32x4 acc[4][4];
#pragma unroll
    for (int i = 0; i < 4; ++i)
#pragma unroll
        for (int j = 0; j < 4; ++j) acc[i][j] = (f32x4){0.f, 0.f, 0.f, 0.f};

    for (int k0 = 0; k0 < K; k0 += 32) {
        {
            int r = tid >> 1, kk = (tid & 1) * 16;
            int gr = row0 + r;
            uint4 v0 = {0, 0, 0, 0}, v1 = {0, 0, 0, 0};
            if (gr < M) {
                const ushort_t* sp = A + (size_t)gr * K + k0 + kk;
                v0 = *(const uint4*)sp;
                v1 = *(const uint4*)(sp + 8);
            }
            *(uint4*)(As + r * 32 + kk) = v0;
            *(uint4*)(As + r * 32 + kk + 8) = v1;
        }
        {
            int kk = tid >> 3;
            int n = (tid & 7) * 16;
            const ushort_t* sp = Bm + (size_t)(k0 + kk) * N + col0 + n;
            ushort_t tmp[16];
            if (col0 + n + 16 <= N) {
                *(uint4*)tmp = *(const uint4*)sp;
                *(uint4*)(tmp + 8) = *(const uint4*)(sp + 8);
            } else {
#pragma unroll
                for (int j = 0; j < 16; ++j) {
                    int c = col0 + n + j;
                    tmp[j] = (c < N) ? sp[j] : (ushort_t)0;
                }
            }
#pragma unroll
            for (int j = 0; j < 16; ++j) Bs[(n + j) * 32 + kk] = tmp[j];
        }
        __syncthreads();
        s16x8 af[4], bfr[4];
#pragma unroll
        for (int i = 0; i < 4; ++i)
            af[i] = *(const s16x8*)(As + (wm * 64 + i * 16 + lr) * 32 + lk);
#pragma unroll
        for (int j = 0; j < 4; ++j)
            bfr[j] = *(const s16x8*)(Bs + (wn * 64 + j * 16 + lr) * 32 + lk);
#pragma unroll
        for (int i = 0; i < 4; ++i)
#pragma unroll
            for (int j = 0; j < 4; ++j)
                acc[i][j] = __builtin_amdgcn_mfma_f32_16x16x32_bf16(af[i], bfr[j], acc[i][j], 0, 0, 0);
        __syncthreads();
    }

    const int lrow = (lane >> 4) * 4;
#pragma unroll
    for (int i = 0; i < 4; ++i) {
#pragma unroll
        for (int j = 0; j < 4; ++j) {
            int gr0 = row0 + wm * 64 + i * 16 + lrow;
            int gc = col0 + wn * 64 + j * 16 + lr;
#pragma unroll
            for (int r = 0; r < 4; ++r) {
                int gr = gr0 + r;
                if (gr < M && gc < N) {
                    float v = acc[i][j][r] + bias[gc];
                    if (MODE == 0) {
                        outb[(size_t)gr * N + gc] = f2bf(v);
                    } else {
                        int t = gr >> 5, b = gr & 31;
                        outf[((size_t)(b * TT + t)) * VV + gc] = v;
                    }
                }
            }
        }
    }
}

// ---------------- persistent recurrent kernel ----------------
// 512 blocks (2/CU). Decode: q = bid&7 (XCD heuristic), r = bid>>3 (0..63);
//   pcg = 2q + (r&1)  in 0..15;  bA = r>>1  in 0..31.
// Group = 16 blocks sharing bA (2 per XCD). All cross-block data via LLC
// (agent-scope atomics); 3 group-local 16-way barriers per step, no global.

__device__ __forceinline__ void gbar16(int* cnt, int target) {
    asm volatile("s_waitcnt vmcnt(0)" ::: "memory");   // drain stores to LLC
    __syncthreads();
    if (threadIdx.x == 0) {
        __hip_atomic_fetch_add(cnt, 1, __ATOMIC_RELAXED, __HIP_MEMORY_SCOPE_AGENT);
        while (__hip_atomic_load(cnt, __ATOMIC_RELAXED, __HIP_MEMORY_SCOPE_AGENT) < target)
            __builtin_amdgcn_s_sleep(1);
    }
    __syncthreads();
}

__global__ __launch_bounds__(256) void k_steps(
    const ushort_t* __restrict__ fp, const ushort_t* __restrict__ fb,
    const ushort_t* __restrict__ WdecT, const float* __restrict__ bdec,
    const float* __restrict__ vatt, const float* __restrict__ bfull,
    const ushort_t* __restrict__ Wg2, const ushort_t* __restrict__ gemb,
    float* __restrict__ hbuf, const float* __restrict__ cbuf,
    float* __restrict__ a_glob, float* __restrict__ ctxP, float* __restrict__ Sp,
    ushort_t* __restrict__ Hb, int* __restrict__ bar) {

    __shared__ __align__(16) float hs[8 * 68];      // h padded [kh][68]
    __shared__ __align__(16) float as_[512];
    __shared__ __align__(16) float vs[512];
    __shared__ __align__(16) float cs[512];
    __shared__ __align__(16) float pctx[4 * 520];
    __shared__ float ep[16];
    __shared__ float sS[1];

    const int bid = blockIdx.x, tid = threadIdx.x;
    const float bfull_r = bfull[0];

    const int q = bid & 7, r = bid >> 3;
    const int pcg = 2 * q + (r & 1);
    const int bA = r >> 1;
    int* grpcnt = bar + 576 + bA * 32;

    // phase A: j = tid>>3 (32 j's), kh8 = tid&7 (64 k each)
    const int aj = tid >> 3, akh = tid & 7;
    const int j_abs = pcg * 32 + aj;
    const float bdec_r = bdec[j_abs];
    // phase B: pl = tid>>4 (0..15), ks = tid&15 (32 k each)
    const int pl = tid >> 4, ks = tid & 15;
    const int cnt_b = (pcg < 4) ? 13 : 12;
    const int p0 = (pcg < 4) ? pcg * 13 : 52 + (pcg - 4) * 12;
    const int ps = tid >> 6, cg = tid & 63;   // ctx partial
    // phase C: R = tid>>1 (row 0..127: d_local*4+gate), kh = tid&1 (K half)
    const int R = tid >> 1, ckh = tid & 1;
    const int cd = pcg * 32 + (R >> 2);
    const int cgate = R & 3;
    const int crow = cgate * DEC + cd;
    const ushort_t* wgp = Wg2 + ((size_t)(pcg * 2 + ckh) * 64) * 1024 + R * 8;

    float creg = ((tid & 7) == 0) ? cbuf[bA * DEC + cd] : 0.f;

    vs[tid] = vatt[tid];
    vs[tid + 256] = vatt[tid + 256];
    __syncthreads();

    for (int st = 0; st < TT; ++st) {
        const float* h_in = hbuf + (size_t)(st & 1) * BB * DEC;
        float* h_out = hbuf + (size_t)((st + 1) & 1) * BB * DEC;

        // ---------- phase A: a[bA][pcg*32..+32] = h@Wdec + bdec ----------
        {
            float2 hv = aload2(h_in + bA * DEC + 2 * tid);
            int k0 = 2 * tid, k1 = 2 * tid + 1;
            hs[(k0 >> 6) * 68 + (k0 & 63)] = hv.x;
            hs[(k1 >> 6) * 68 + (k1 & 63)] = hv.y;
        }
        __syncthreads();
        {
            const ushort_t* wp = WdecT + (size_t)j_abs * 512 + akh * 64;
            const float* hp = hs + akh * 68;
            float acc = 0.f;
#pragma unroll
            for (int c = 0; c < 8; ++c) {
                uint4 wv = *(const uint4*)(wp + c * 8);
                f32x4 x0 = *(const f32x4*)(hp + c * 8);
                f32x4 x1 = *(const f32x4*)(hp + c * 8 + 4);
                acc += bflo(wv.x) * x0[0] + bfhi(wv.x) * x0[1]
                     + bflo(wv.y) * x0[2] + bfhi(wv.y) * x0[3]
                     + bflo(wv.z) * x1[0] + bfhi(wv.z) * x1[1]
                     + bflo(wv.w) * x1[2] + bfhi(wv.w) * x1[3];
            }
            acc += __shfl_xor(acc, 1);
            acc += __shfl_xor(acc, 2);
            acc += __shfl_xor(acc, 4);
            if (akh == 0) astore1(a_glob + bA * ATTD + j_abs, acc + bdec_r);
        }
        gbar16(grpcnt, 16 * (3 * st + 1));

        // ---------- phase B: scores -> exp -> partial ctx/S (no atomics) ----------
        {
            float2 av = aload2(a_glob + bA * ATTD + 2 * tid);
            as_[2 * tid] = av.x;
            as_[2 * tid + 1] = av.y;
        }
        __syncthreads();
        {
            float acc = 0.f;
            if (pl < cnt_b) {
                const int p = p0 + pl;
                const ushort_t* fr = fp + ((size_t)bA * PP + p) * ATTD + ks * 32;
#pragma unroll
                for (int c2 = 0; c2 < 4; ++c2) {
                    uint4 fv = *(const uint4*)(fr + c2 * 8);
                    const int k = ks * 32 + c2 * 8;
                    const float* ap = as_ + k;
                    const float* vp = vs + k;
                    acc += ftanh(bflo(fv.x) + ap[0]) * vp[0];
                    acc += ftanh(bfhi(fv.x) + ap[1]) * vp[1];
                    acc += ftanh(bflo(fv.y) + ap[2]) * vp[2];
                    acc += ftanh(bfhi(fv.y) + ap[3]) * vp[3];
                    acc += ftanh(bflo(fv.z) + ap[4]) * vp[4];
                    acc += ftanh(bfhi(fv.z) + ap[5]) * vp[5];
                    acc += ftanh(bflo(fv.w) + ap[6]) * vp[6];
                    acc += ftanh(bfhi(fv.w) + ap[7]) * vp[7];
                }
            }
            acc += __shfl_xor(acc, 1);
            acc += __shfl_xor(acc, 2);
            acc += __shfl_xor(acc, 4);
            acc += __shfl_xor(acc, 8);
            if (ks == 0) ep[pl] = (pl < cnt_b) ? __expf(acc + bfull_r) : 0.f;
        }
        __syncthreads();
        if (tid < 16) {
            float v = ep[tid];
            v += __shfl_xor(v, 1);
            v += __shfl_xor(v, 2);
            v += __shfl_xor(v, 4);
            v += __shfl_xor(v, 8);
            if (tid == 0) astore1(Sp + bA * 16 + pcg, v);
        }
        {
            float a8[8];
#pragma unroll
            for (int i2 = 0; i2 < 8; ++i2) a8[i2] = 0.f;
            for (int p2 = ps; p2 < cnt_b; p2 += 4) {
                float e2 = ep[p2];
                uint4 fv = *(const uint4*)(fb + ((size_t)bA * PP + p0 + p2) * ENC + cg * 8);
                a8[0] += e2 * bflo(fv.x); a8[1] += e2 * bfhi(fv.x);
                a8[2] += e2 * bflo(fv.y); a8[3] += e2 * bfhi(fv.y);
                a8[4] += e2 * bflo(fv.z); a8[5] += e2 * bfhi(fv.z);
                a8[6] += e2 * bflo(fv.w); a8[7] += e2 * bfhi(fv.w);
            }
            float* pp = pctx + ps * 520 + cg * 8;
            *(f32x4*)pp = (f32x4){a8[0], a8[1], a8[2], a8[3]};
            *(f32x4*)(pp + 4) = (f32x4){a8[4], a8[5], a8[6], a8[7]};
        }
        __syncthreads();
        {
            int c0i = 2 * tid, c1i = 2 * tid + 1;
            float s0 = pctx[c0i] + pctx[520 + c0i] + pctx[1040 + c0i] + pctx[1560 + c0i];
            float s1 = pctx[c1i] + pctx[520 + c1i] + pctx[1040 + c1i] + pctx[1560 + c1i];
            float* cp = ctxP + ((size_t)bA * 16 + pcg) * 512;
            astore1(cp + c0i, s0);
            astore1(cp + c1i, s1);
        }
        gbar16(grpcnt, 16 * (3 * st + 2));

        // ---------- phase C: sum partials, gate GEMV (LDS x, L2 W), LSTM ----------
        {
            if (tid < 16) {
                float s = aload1(Sp + bA * 16 + tid);
                s += __shfl_xor(s, 1);
                s += __shfl_xor(s, 2);
                s += __shfl_xor(s, 4);
                s += __shfl_xor(s, 8);
                if (tid == 0) sS[0] = s;
            }
            __syncthreads();
            const float invS = 1.f / sS[0];
            float s0 = 0.f, s1 = 0.f;
            const float* cp = ctxP + (size_t)bA * 16 * 512 + 2 * tid;
#pragma unroll
            for (int sl = 0; sl < 16; ++sl) {
                float2 v = aload2(cp + sl * 512);
                s0 += v.x;
                s1 += v.y;
            }
            cs[2 * tid] = s0 * invS;
            cs[2 * tid + 1] = s1 * invS;
        }
        __syncthreads();
        {
            float acc = 0.f;
#pragma unroll 8
            for (int kc = 0; kc < 64; ++kc) {
                uint4 wv = *(const uint4*)(wgp + kc * 1024);
                const float* xp = ckh ? (hs + (kc >> 3) * 68 + (kc & 7) * 8) : (cs + kc * 8);
                f32x4 x0 = *(const f32x4*)xp;
                f32x4 x1 = *(const f32x4*)(xp + 4);
                acc += bflo(wv.x) * x0[0] + bfhi(wv.x) * x0[1]
                     + bflo(wv.y) * x0[2] + bfhi(wv.y) * x0[3]
                     + bflo(wv.z) * x1[0] + bfhi(wv.z) * x1[1]
                     + bflo(wv.w) * x1[2] + bfhi(wv.w) * x1[3];
            }
            acc += __shfl_xor(acc, 1);       // combine K halves
            const size_t trow = (size_t)st * BB + bA;
            acc += bf2f(gemb[trow * (4 * DEC) + crow]);
            float pf = __shfl_xor(acc, 2);
            float pg = __shfl_xor(acc, 4);
            float po = __shfl_xor(acc, 6);
            if ((tid & 7) == 0) {
                float cn = fsig(pf) * creg + fsig(acc) * ftanh(pg);
                float hn = fsig(po) * ftanh(cn);
                creg = cn;
                astore1(h_out + bA * DEC + cd, hn);
                Hb[trow * DEC + cd] = f2bf(hn);
            }
        }
        gbar16(grpcnt, 16 * (3 * st + 3));
    }
}

// ---------------- launch ----------------

extern "C" void kernel_launch(void* const* d_in, const int* in_sizes, int n_in,
                              void* d_out, int out_size, void* d_ws, size_t ws_size,
                              hipStream_t stream) {
    const float* features  = (const float*)d_in[0];
    const int*   captions  = (const int*)d_in[1];
    const float* emb       = (const float*)d_in[2];
    const float* W_enc_att = (const float*)d_in[3];
    const float* b_enc_att = (const float*)d_in[4];
    const float* W_dec_att = (const float*)d_in[5];
    const float* b_dec_att = (const float*)d_in[6];
    const float* v_att     = (const float*)d_in[7];
    const float* b_full    = (const float*)d_in[8];
    const float* W_init_h  = (const float*)d_in[9];
    const float* b_init_h  = (const float*)d_in[10];
    const float* W_init_c  = (const float*)d_in[11];
    const float* b_init_c  = (const float*)d_in[12];
    const float* W_ih      = (const float*)d_in[13];
    const float* W_hh      = (const float*)d_in[14];
    const float* b_ih      = (const float*)d_in[15];
    const float* b_hh      = (const float*)d_in[16];
    const float* W_fcn     = (const float*)d_in[17];
    const float* b_fcn     = (const float*)d_in[18];
    float* out = (float*)d_out;
    char* ws = (char*)d_ws;

    size_t o = 0;
    ushort_t* Wfcn_b  = (ushort_t*)(ws + o); o += (size_t)DEC * VV * 2;
    ushort_t* Wenc_b  = (ushort_t*)(ws + o); o += (size_t)ENC * ATTD * 2;
    ushort_t* WdecT   = (ushort_t*)(ws + o); o += (size_t)DEC * ATTD * 2;
    ushort_t* fb      = (ushort_t*)(ws + o); o += (size_t)BB * PP * ENC * 2;
    ushort_t* fp_b    = (ushort_t*)(ws + o); o += (size_t)BB * PP * ATTD * 2;
    ushort_t* emb_bf  = (ushort_t*)(ws + o); o += (size_t)TT * BB * EE * 2;
    ushort_t* WihT    = (ushort_t*)(ws + o); o += (size_t)EE * 4 * DEC * 2;
    ushort_t* gembuf  = (ushort_t*)(ws + o); o += (size_t)TT * BB * 4 * DEC * 2;
    ushort_t* Wg2     = (ushort_t*)(ws + o); o += (size_t)4 * DEC * 1024 * 2;  // 4 MB
    float*    bsum    = (float*)(ws + o);    o += (size_t)4 * DEC * 4;
    ushort_t* Hb      = (ushort_t*)(ws + o); o += (size_t)TT * BB * DEC * 2;
    float*    hbuf    = (float*)(ws + o);    o += (size_t)2 * BB * DEC * 4;
    float*    cbuf    = (float*)(ws + o);    o += (size_t)BB * DEC * 4;
    float*    a_glob  = (float*)(ws + o);    o += (size_t)BB * ATTD * 4;
    float*    ctxP    = (float*)(ws + o);    o += (size_t)BB * 16 * 512 * 4;   // 1 MB
    float*    Sp      = (float*)(ws + o);    o += (size_t)BB * 16 * 4 + 64;
    int*      bar     = (int*)(ws + o);      o += 4096 * 4;

    // prep
    k_cvt<<<2048, 256, 0, stream>>>(W_fcn, Wfcn_b, DEC * VV);
    k_cvt<<<256, 256, 0, stream>>>(W_enc_att, Wenc_b, ENC * ATTD);
    k_cvtD<<<256, 256, 0, stream>>>(W_dec_att, WdecT);
    k_cvt<<<2048, 256, 0, stream>>>(features, fb, BB * PP * ENC);
    k_embed_bf<<<1024, 256, 0, stream>>>(captions, emb, emb_bf);
    k_cvtT<<<1024, 256, 0, stream>>>(W_ih, WihT);
    k_cvtG2<<<4096, 256, 0, stream>>>(W_ih, W_hh, Wg2);
    k_bsum<<<8, 256, 0, stream>>>(b_ih, b_hh, bsum, 4 * DEC);
    k_init<<<32, 256, 0, stream>>>(features, W_init_h, b_init_h, W_init_c, b_init_c,
                                   hbuf, cbuf, bar);
    // feat_proj = features @ W_enc_att + b_enc_att (bf16)
    k_gemm<0><<<dim3((BB * PP) / 128, ATTD / 128), 256, 0, stream>>>(
        fb, Wenc_b, b_enc_att, fp_b, nullptr, BB * PP, ATTD, ENC);
    // gates_emb = embeds @ W_ih[:, :256]^T + (b_ih + b_hh)  (bf16)
    k_gemm<0><<<dim3((TT * BB + 127) / 128, (4 * DEC) / 128), 256, 0, stream>>>(
        emb_bf, WihT, bsum, gembuf, nullptr, TT * BB, 4 * DEC, EE);

    // persistent recurrent kernel: 512 blocks, 3 group-local 16-way barriers/step
    k_steps<<<NBLK, 256, 0, stream>>>(fp_b, fb, WdecT, b_dec_att, v_att, b_full,
                                      Wg2, gembuf, hbuf, cbuf,
                                      a_glob, ctxP, Sp, Hb, bar);

    // out = H @ W_fcn + b_fcn, scattered to [b][t][v]
    k_gemm<1><<<dim3((TT * BB + 127) / 128, (VV + 127) / 128), 256, 0, stream>>>(
        Hb, Wfcn_b, b_fcn, nullptr, out, TT * BB, VV, DEC);
}